// Round 3
// baseline (48013.641 us; speedup 1.0000x reference)
//
#include <hip/hip_runtime.h>
#include <stdint.h>
#include <math.h>

#define N_TOT 131072   // NSEQ * T
#define TSEQ  2048
#define NSEQ  64
#define CS    128      // chunk steps
#define NCH   16       // chunks
#define NSEQG 4        // LSTM seq groups
#define NSLICE 32      // LSTM slices (WGs) per group
#define UPS   8        // hidden units per slice

// ---------------------------------------------------------------------------
__global__ __launch_bounds__(256)
void zero_u32(unsigned int* __restrict__ p, int n)
{
    int i = blockIdx.x * 256 + threadIdx.x;
    if (i < n) p[i] = 0u;
}

// ---------------------------------------------------------------------------
// gemm_xg (chunk): xg[(seq*CS+tl)*1024+n] = feats[gr] @ W_ih^T + b_ih + b_hh
// grid (8, 64): bx = n-tile, by = seq. gr = seq*TSEQ + base + m, m=0..127
// fp32, 128x128 tile, BK=16, 8x8 reg block.
// ---------------------------------------------------------------------------
__global__ __launch_bounds__(256)
void gemm_xg(const float* __restrict__ A, const float* __restrict__ Wih,
             const float* __restrict__ bih, const float* __restrict__ bhh,
             float* __restrict__ xg, int base)
{
    __shared__ float As[16][136];
    __shared__ float Bs[16][136];
    const int t  = threadIdx.x;
    const int n0 = blockIdx.x * 128;
    const int seq = blockIdx.y;
    const size_t grow0 = (size_t)seq * TSEQ + base;
    const size_t lrow0 = (size_t)seq * CS;
    const int tx = t & 15, ty = t >> 4;

    float acc[8][8];
#pragma unroll
    for (int i = 0; i < 8; ++i)
#pragma unroll
        for (int j = 0; j < 8; ++j) acc[i][j] = 0.f;

    for (int kt = 0; kt < 256; kt += 16) {
#pragma unroll
        for (int jj = 0; jj < 2; ++jj) {
            int idx = t + 256 * jj;
            int m = idx >> 2, q = idx & 3;
            float4 a = *(const float4*)(A + (grow0 + m) * 256 + kt + q * 4);
            As[q * 4 + 0][m] = a.x; As[q * 4 + 1][m] = a.y;
            As[q * 4 + 2][m] = a.z; As[q * 4 + 3][m] = a.w;
            float4 b = *(const float4*)(Wih + (size_t)(n0 + m) * 256 + kt + q * 4);
            Bs[q * 4 + 0][m] = b.x; Bs[q * 4 + 1][m] = b.y;
            Bs[q * 4 + 2][m] = b.z; Bs[q * 4 + 3][m] = b.w;
        }
        __syncthreads();
#pragma unroll
        for (int k = 0; k < 16; ++k) {
            float4 a0 = *(const float4*)&As[k][ty * 8];
            float4 a1 = *(const float4*)&As[k][ty * 8 + 4];
            float4 b0 = *(const float4*)&Bs[k][tx * 8];
            float4 b1 = *(const float4*)&Bs[k][tx * 8 + 4];
            float av[8] = {a0.x, a0.y, a0.z, a0.w, a1.x, a1.y, a1.z, a1.w};
            float bv[8] = {b0.x, b0.y, b0.z, b0.w, b1.x, b1.y, b1.z, b1.w};
#pragma unroll
            for (int i = 0; i < 8; ++i)
#pragma unroll
                for (int j = 0; j < 8; ++j) acc[i][j] += av[i] * bv[j];
        }
        __syncthreads();
    }
#pragma unroll
    for (int i = 0; i < 8; ++i) {
        size_t lr = lrow0 + ty * 8 + i;
#pragma unroll
        for (int j = 0; j < 8; ++j) {
            int n = n0 + tx * 8 + j;
            xg[lr * 1024 + n] = acc[i][j] + bih[n] + bhh[n];
        }
    }
}

// ---------------------------------------------------------------------------
// gemm_latent (chunk): lat[lr][n] (n<768: f1 = feats@W_feat[0:768]^T + b_feat;
// n>=768: out_pi = feats@W_emb^T + b_emb). fp64 master accumulators.
// grid (16, 64): bx = 64-col tile, by = seq. 128x64 tile, 8x4/thread.
// ---------------------------------------------------------------------------
__global__ __launch_bounds__(256)
void gemm_latent(const float* __restrict__ A, const float* __restrict__ Wfeat,
                 const float* __restrict__ Wemb, const float* __restrict__ bfeat,
                 const float* __restrict__ bemb, float* __restrict__ lat, int base)
{
    __shared__ float As[16][136];
    __shared__ float Bs[16][72];
    const int t  = threadIdx.x;
    const int n0 = blockIdx.x * 64;
    const int seq = blockIdx.y;
    const size_t grow0 = (size_t)seq * TSEQ + base;
    const size_t lrow0 = (size_t)seq * CS;
    const int tx = t & 15, ty = t >> 4;

    double acc[8][4];
#pragma unroll
    for (int i = 0; i < 8; ++i)
#pragma unroll
        for (int j = 0; j < 4; ++j) acc[i][j] = 0.0;

    for (int kt = 0; kt < 256; kt += 16) {
#pragma unroll
        for (int jj = 0; jj < 2; ++jj) {
            int idx = t + 256 * jj;
            int m = idx >> 2, q = idx & 3;
            float4 a = *(const float4*)(A + (grow0 + m) * 256 + kt + q * 4);
            As[q * 4 + 0][m] = a.x; As[q * 4 + 1][m] = a.y;
            As[q * 4 + 2][m] = a.z; As[q * 4 + 3][m] = a.w;
        }
        {
            int m = t >> 2, q = t & 3;
            int n = n0 + m;
            const float* Brow = (n < 768) ? (Wfeat + (size_t)n * 256)
                                          : (Wemb + (size_t)(n - 768) * 256);
            float4 b = *(const float4*)(Brow + kt + q * 4);
            Bs[q * 4 + 0][m] = b.x; Bs[q * 4 + 1][m] = b.y;
            Bs[q * 4 + 2][m] = b.z; Bs[q * 4 + 3][m] = b.w;
        }
        __syncthreads();
        float p[8][4];
#pragma unroll
        for (int i = 0; i < 8; ++i)
#pragma unroll
            for (int j = 0; j < 4; ++j) p[i][j] = 0.f;
#pragma unroll
        for (int k = 0; k < 16; ++k) {
            float4 a0 = *(const float4*)&As[k][ty * 8];
            float4 a1 = *(const float4*)&As[k][ty * 8 + 4];
            float4 b0 = *(const float4*)&Bs[k][tx * 4];
            float av[8] = {a0.x, a0.y, a0.z, a0.w, a1.x, a1.y, a1.z, a1.w};
            float bv[4] = {b0.x, b0.y, b0.z, b0.w};
#pragma unroll
            for (int i = 0; i < 8; ++i)
#pragma unroll
                for (int j = 0; j < 4; ++j) p[i][j] += av[i] * bv[j];
        }
#pragma unroll
        for (int i = 0; i < 8; ++i)
#pragma unroll
            for (int j = 0; j < 4; ++j) acc[i][j] += (double)p[i][j];
        __syncthreads();
    }
#pragma unroll
    for (int i = 0; i < 8; ++i) {
        size_t lr = lrow0 + ty * 8 + i;
#pragma unroll
        for (int j = 0; j < 4; ++j) {
            int n = n0 + tx * 4 + j;
            float v = (float)acc[i][j];
            v += (n < 768) ? bfeat[n] : bemb[n - 768];
            lat[lr * 1024 + n] = v;
        }
    }
}

// ---------------------------------------------------------------------------
// gemm_h1p (chunk): h1[lr][n] = relu(lat[lr] @ Wp1[n]^T + bp1[n]), K=1024.
// fp64 master accumulators. grid (8, 64). 128x64 tile, 8x4/thread.
// ---------------------------------------------------------------------------
__global__ __launch_bounds__(256)
void gemm_h1p(const float* __restrict__ lat, const float* __restrict__ Wp1,
              const float* __restrict__ bp1, float* __restrict__ h1)
{
    __shared__ float As[16][136];
    __shared__ float Bs[16][72];
    const int t  = threadIdx.x;
    const int n0 = blockIdx.x * 64;
    const size_t lrow0 = (size_t)blockIdx.y * 128;
    const int tx = t & 15, ty = t >> 4;

    double acc[8][4];
#pragma unroll
    for (int i = 0; i < 8; ++i)
#pragma unroll
        for (int j = 0; j < 4; ++j) acc[i][j] = 0.0;

    for (int kt = 0; kt < 1024; kt += 16) {
#pragma unroll
        for (int jj = 0; jj < 2; ++jj) {
            int idx = t + 256 * jj;
            int m = idx >> 2, q = idx & 3;
            float4 a = *(const float4*)(lat + (lrow0 + m) * 1024 + kt + q * 4);
            As[q * 4 + 0][m] = a.x; As[q * 4 + 1][m] = a.y;
            As[q * 4 + 2][m] = a.z; As[q * 4 + 3][m] = a.w;
        }
        {
            int m = t >> 2, q = t & 3;
            float4 b = *(const float4*)(Wp1 + (size_t)(n0 + m) * 1024 + kt + q * 4);
            Bs[q * 4 + 0][m] = b.x; Bs[q * 4 + 1][m] = b.y;
            Bs[q * 4 + 2][m] = b.z; Bs[q * 4 + 3][m] = b.w;
        }
        __syncthreads();
        float p[8][4];
#pragma unroll
        for (int i = 0; i < 8; ++i)
#pragma unroll
            for (int j = 0; j < 4; ++j) p[i][j] = 0.f;
#pragma unroll
        for (int k = 0; k < 16; ++k) {
            float4 a0 = *(const float4*)&As[k][ty * 8];
            float4 a1 = *(const float4*)&As[k][ty * 8 + 4];
            float4 b0 = *(const float4*)&Bs[k][tx * 4];
            float av[8] = {a0.x, a0.y, a0.z, a0.w, a1.x, a1.y, a1.z, a1.w};
            float bv[4] = {b0.x, b0.y, b0.z, b0.w};
#pragma unroll
            for (int i = 0; i < 8; ++i)
#pragma unroll
                for (int j = 0; j < 4; ++j) p[i][j] += av[i] * bv[j];
        }
#pragma unroll
        for (int i = 0; i < 8; ++i)
#pragma unroll
            for (int j = 0; j < 4; ++j) acc[i][j] += (double)p[i][j];
        __syncthreads();
    }
#pragma unroll
    for (int i = 0; i < 8; ++i) {
        size_t lr = lrow0 + ty * 8 + i;
#pragma unroll
        for (int j = 0; j < 4; ++j) {
            int n = n0 + tx * 4 + j;
            float v = (float)acc[i][j];
            v += bp1[n];
            h1[lr * 512 + n] = v > 0.f ? v : 0.f;
        }
    }
}

// ---------------------------------------------------------------------------
// gemm_h1v (chunk): h1[lr][n] = relu(lat[lr][0:768]@Wv1[n][0:768]^T
//                                  + hs[lr]@Wv1[n][768:]^T + bv1[n])
// fp32. grid (4, 64): 128x128 tile, 8x8/thread.
// ---------------------------------------------------------------------------
__global__ __launch_bounds__(256)
void gemm_h1v(const float* __restrict__ lat, const float* __restrict__ hs,
              const float* __restrict__ Wv1, const float* __restrict__ bv1,
              float* __restrict__ h1)
{
    __shared__ float As[16][136];
    __shared__ float Bs[16][136];
    const int t  = threadIdx.x;
    const int n0 = blockIdx.x * 128;
    const size_t lrow0 = (size_t)blockIdx.y * 128;
    const int tx = t & 15, ty = t >> 4;

    float acc[8][8];
#pragma unroll
    for (int i = 0; i < 8; ++i)
#pragma unroll
        for (int j = 0; j < 8; ++j) acc[i][j] = 0.f;

    for (int pass = 0; pass < 2; ++pass) {
        const float* A  = (pass == 0) ? lat : hs;
        const int lda   = (pass == 0) ? 1024 : 256;
        const int kmax  = (pass == 0) ? 768 : 256;
        const int boff  = (pass == 0) ? 0 : 768;
        for (int kt = 0; kt < kmax; kt += 16) {
#pragma unroll
            for (int jj = 0; jj < 2; ++jj) {
                int idx = t + 256 * jj;
                int m = idx >> 2, q = idx & 3;
                float4 a = *(const float4*)(A + (lrow0 + m) * lda + kt + q * 4);
                As[q * 4 + 0][m] = a.x; As[q * 4 + 1][m] = a.y;
                As[q * 4 + 2][m] = a.z; As[q * 4 + 3][m] = a.w;
                float4 b = *(const float4*)(Wv1 + (size_t)(n0 + m) * 1024 + boff + kt + q * 4);
                Bs[q * 4 + 0][m] = b.x; Bs[q * 4 + 1][m] = b.y;
                Bs[q * 4 + 2][m] = b.z; Bs[q * 4 + 3][m] = b.w;
            }
            __syncthreads();
#pragma unroll
            for (int k = 0; k < 16; ++k) {
                float4 a0 = *(const float4*)&As[k][ty * 8];
                float4 a1 = *(const float4*)&As[k][ty * 8 + 4];
                float4 b0 = *(const float4*)&Bs[k][tx * 8];
                float4 b1 = *(const float4*)&Bs[k][tx * 8 + 4];
                float av[8] = {a0.x, a0.y, a0.z, a0.w, a1.x, a1.y, a1.z, a1.w};
                float bv[8] = {b0.x, b0.y, b0.z, b0.w, b1.x, b1.y, b1.z, b1.w};
#pragma unroll
                for (int i = 0; i < 8; ++i)
#pragma unroll
                    for (int j = 0; j < 8; ++j) acc[i][j] += av[i] * bv[j];
            }
            __syncthreads();
        }
    }
#pragma unroll
    for (int i = 0; i < 8; ++i) {
        size_t lr = lrow0 + ty * 8 + i;
#pragma unroll
        for (int j = 0; j < 8; ++j) {
            int n = n0 + tx * 8 + j;
            float v = acc[i][j] + bv1[n];
            h1[lr * 512 + n] = v > 0.f ? v : 0.f;
        }
    }
}

// ---------------------------------------------------------------------------
// lstm_chunk: 128 WGs = 4 groups(16 seqs) x 32 slices(8 units). CS steps from
// global step base. h exchanged cross-WG via global double buffer + flags
// (agent-scope atomics). c persists in cstate across chunk launches.
// ---------------------------------------------------------------------------
__global__ __launch_bounds__(256)
void lstm_chunk(const float* __restrict__ xg, const float* __restrict__ starts,
                const float* __restrict__ h0g, const float* __restrict__ c0g,
                float* __restrict__ cstate, const float* __restrict__ Whh,
                float* __restrict__ hs, float* __restrict__ hT,
                float* __restrict__ cT,
                float* __restrict__ hxc, unsigned int* __restrict__ flags,
                int base)
{
    __shared__ float Wl[4][UPS][260];
    __shared__ float hl[16][260];
    __shared__ float gb[16][UPS][4];
    __shared__ float stl[16];

    const int t  = threadIdx.x;
    const int wg = blockIdx.x;
    const int g  = wg >> 5;
    const int sl = wg & 31;
    const int u0 = sl * UPS;

    for (int j = 0; j < 32; ++j) {
        int f = t + 256 * j;
        int gg = f >> 11;
        int rem = f & 2047;
        int u = rem >> 8;
        int k = rem & 255;
        Wl[gg][u][k] = Whh[(size_t)(gg * 256 + u0 + u) * 256 + k];
    }

    const int s_i  = t & 15;
    const int x    = t >> 4;
    const int uu   = x & 7;
    const int gsel = x >> 3;
    const int seq  = g * 16 + s_i;
    const bool upd = (t < 128);

    float creg = 0.f;
    if (upd) {
        const float* csrc = (base == 0) ? c0g : cstate;
        creg = csrc[(size_t)seq * 256 + u0 + x];
    }

    float* hx_base = hxc + (size_t)g * 2 * 4096;
    unsigned int* flg = flags + (size_t)g * TSEQ;
    __syncthreads();

    for (int lt = 0; lt < CS; ++lt) {
        const int S = base + lt;
        float xgi = 0.f, xgf = 0.f, xgg = 0.f, xgo = 0.f;
        if (upd) {
            const float* xr = xg + ((size_t)seq * CS + lt) * 1024 + (u0 + x);
            xgi = xr[0]; xgf = xr[256]; xgg = xr[512]; xgo = xr[768];
        }
        if (t < 16) stl[t] = starts[(size_t)(g * 16 + t) * TSEQ + S];

        if (S > 0 && t == 0) {
            unsigned spins = 0;
            while (__hip_atomic_load(&flg[S - 1], __ATOMIC_ACQUIRE,
                                     __HIP_MEMORY_SCOPE_AGENT) < (unsigned)NSLICE) {
                __builtin_amdgcn_s_sleep(2);
                if (++spins > (1u << 18)) break;
            }
        }
        __syncthreads();

        if (S == 0) {
#pragma unroll
            for (int j = 0; j < 16; ++j) {
                int f = t + 256 * j; int u = f >> 4; int s = f & 15;
                hl[s][u] = h0g[(size_t)(g * 16 + s) * 256 + u] * (1.f - stl[s]);
            }
        } else {
            const float* src = hx_base + (size_t)(S & 1) * 4096;
#pragma unroll
            for (int j = 0; j < 16; ++j) {
                int f = t + 256 * j; int u = f >> 4; int s = f & 15;
                float v = __hip_atomic_load(&src[f], __ATOMIC_RELAXED,
                                            __HIP_MEMORY_SCOPE_AGENT);
                hl[s][u] = v * (1.f - stl[s]);
            }
        }
        __syncthreads();

        const float* w0 = &Wl[gsel * 2][uu][0];
        const float* w1 = &Wl[gsel * 2 + 1][uu][0];
        const float* hr = &hl[s_i][0];
        float a0 = 0.f, a1 = 0.f;
#pragma unroll 8
        for (int k = 0; k < 256; k += 4) {
            float4 hv = *(const float4*)(hr + k);
            float4 wa = *(const float4*)(w0 + k);
            float4 wb = *(const float4*)(w1 + k);
            a0 += hv.x * wa.x + hv.y * wa.y + hv.z * wa.z + hv.w * wa.w;
            a1 += hv.x * wb.x + hv.y * wb.y + hv.z * wb.z + hv.w * wb.w;
        }
        gb[s_i][uu][gsel * 2]     = a0;
        gb[s_i][uu][gsel * 2 + 1] = a1;
        __syncthreads();

        if (upd) {
            float pi_ = gb[s_i][x][0] + xgi;
            float pf_ = gb[s_i][x][1] + xgf;
            float pg_ = gb[s_i][x][2] + xgg;
            float po_ = gb[s_i][x][3] + xgo;
            float ms = 1.f - stl[s_i];
            float c = creg * ms;
            float si = 1.f / (1.f + expf(-pi_));
            float sf = 1.f / (1.f + expf(-pf_));
            float so = 1.f / (1.f + expf(-po_));
            c = sf * c + si * tanhf(pg_);
            float h = so * tanhf(c);
            creg = c;
            __hip_atomic_store(&hx_base[(size_t)((S + 1) & 1) * 4096 + (u0 + x) * 16 + s_i],
                               h, __ATOMIC_RELAXED, __HIP_MEMORY_SCOPE_AGENT);
            hs[((size_t)seq * CS + lt) * 256 + u0 + x] = h;
            if (lt == CS - 1) cstate[(size_t)seq * 256 + u0 + x] = c;
            if (S == TSEQ - 1) {
                hT[(size_t)seq * 256 + u0 + x] = h;
                cT[(size_t)seq * 256 + u0 + x] = c;
            }
        }
        __threadfence();
        __syncthreads();
        if (t == 0)
            __hip_atomic_fetch_add(&flg[S], 1u, __ATOMIC_RELEASE,
                                   __HIP_MEMORY_SCOPE_AGENT);
    }
}

// ---------------------------------------------------------------------------
__global__ __launch_bounds__(256)
void mask_kernel(const float* __restrict__ starts, const float* __restrict__ h_pi,
                 const float* __restrict__ c_pi,
                 float* __restrict__ o_hpi, float* __restrict__ o_cpi)
{
    __shared__ float red[256];
    const int n = blockIdx.x, t = threadIdx.x;
    float a = 0.f;
    for (int j = 0; j < 8; ++j)
        a = fmaxf(a, starts[(size_t)n * TSEQ + t * 8 + j]);
    red[t] = a; __syncthreads();
    for (int s = 128; s > 0; s >>= 1) {
        if (t < s) red[t] = fmaxf(red[t], red[t + s]);
        __syncthreads();
    }
    float m = (red[0] > 0.f) ? 0.f : 1.f;
    o_hpi[(size_t)n * 256 + t] = h_pi[(size_t)n * 256 + t] * m;
    o_cpi[(size_t)n * 256 + t] = c_pi[(size_t)n * 256 + t] * m;
}

// ---------------------------------------------------------------------------
// policy_finish (chunk): logits (fp64 dot) -> argmax, log-softmax pick.
// 8 rows x 32 lanes per block; 1024 blocks.
// ---------------------------------------------------------------------------
__global__ __launch_bounds__(256)
void policy_finish(const float* __restrict__ h1p, const float* __restrict__ Wp2,
                   const float* __restrict__ bp2,
                   float* __restrict__ o_actions, float* __restrict__ o_logp,
                   int base)
{
    __shared__ float w2t[512 * 32];   // [k][c]
    const int t = threadIdx.x;
    for (int j = 0; j < 64; ++j) {
        int idx = t + 256 * j;
        int k = idx >> 5, c = idx & 31;
        w2t[idx] = Wp2[(size_t)c * 512 + k];
    }
    __syncthreads();

    const int c = t & 31;
    size_t lr = (size_t)blockIdx.x * 8 + (t >> 5);
    size_t grow = (lr >> 7) * TSEQ + base + (lr & 127);
    const float* hrow = h1p + lr * 512;
    double s = 0.0;
    for (int k = 0; k < 512; k += 4) {
        float4 h4 = *(const float4*)(hrow + k);
        s += (double)h4.x * (double)w2t[(k + 0) * 32 + c];
        s += (double)h4.y * (double)w2t[(k + 1) * 32 + c];
        s += (double)h4.z * (double)w2t[(k + 2) * 32 + c];
        s += (double)h4.w * (double)w2t[(k + 3) * 32 + c];
    }
    double logit = s + (double)bp2[c];

    double mv = logit; int mi = c;
#pragma unroll
    for (int off = 16; off >= 1; off >>= 1) {
        double ov = __shfl_xor(mv, off, 32);
        int    oi = __shfl_xor(mi, off, 32);
        if (ov > mv || (ov == mv && oi < mi)) { mv = ov; mi = oi; }
    }
    double se = exp(logit - mv);
#pragma unroll
    for (int off = 16; off >= 1; off >>= 1) se += __shfl_xor(se, off, 32);

    if (c == 0) {
        o_actions[grow] = (float)mi;
        o_logp[grow]    = (float)(-log(se));
    }
}

// ---------------------------------------------------------------------------
// value_finish (chunk): values = h1v . Wv2 + bv2. 64 rows x 4 lanes; 128 blocks.
// ---------------------------------------------------------------------------
__global__ __launch_bounds__(256)
void value_finish(const float* __restrict__ h1v, const float* __restrict__ Wv2,
                  const float* __restrict__ bv2, float* __restrict__ o_values,
                  int base)
{
    __shared__ float wv[512];
    const int t = threadIdx.x;
    wv[t] = Wv2[t]; wv[t + 256] = Wv2[t + 256];
    __syncthreads();
    const int q = t & 3;
    size_t lr = (size_t)blockIdx.x * 64 + (t >> 2);
    size_t grow = (lr >> 7) * TSEQ + base + (lr & 127);
    const float* hrow = h1v + lr * 512;
    float s = 0.f;
    for (int k = q * 128; k < q * 128 + 128; k += 4) {
        float4 h4 = *(const float4*)(hrow + k);
        float4 w4 = *(const float4*)&wv[k];
        s += h4.x * w4.x + h4.y * w4.y + h4.z * w4.z + h4.w * w4.w;
    }
    s += __shfl_xor(s, 1, 4);
    s += __shfl_xor(s, 2, 4);
    if (q == 0) o_values[grow] = s + bv2[0];
}

// ---------------------------------------------------------------------------
extern "C" void kernel_launch(void* const* d_in, const int* in_sizes, int n_in,
                              void* d_out, int out_size, void* d_ws, size_t ws_size,
                              hipStream_t stream)
{
    const float* features = (const float*)d_in[0];
    const float* starts   = (const float*)d_in[1];
    const float* h_pi     = (const float*)d_in[2];
    const float* c_pi     = (const float*)d_in[3];
    const float* h_vf     = (const float*)d_in[4];
    const float* c_vf     = (const float*)d_in[5];
    const float* W_feat   = (const float*)d_in[6];
    const float* b_feat   = (const float*)d_in[7];
    const float* W_emb    = (const float*)d_in[8];
    const float* b_emb    = (const float*)d_in[9];
    const float* W_ih     = (const float*)d_in[10];
    const float* W_hh     = (const float*)d_in[11];
    const float* b_ih     = (const float*)d_in[12];
    const float* b_hh     = (const float*)d_in[13];
    const float* Wp1      = (const float*)d_in[14];
    const float* bp1      = (const float*)d_in[15];
    const float* Wp2      = (const float*)d_in[16];
    const float* bp2      = (const float*)d_in[17];
    const float* Wv1      = (const float*)d_in[18];
    const float* bv1      = (const float*)d_in[19];
    const float* Wv2      = (const float*)d_in[20];
    const float* bv2      = (const float*)d_in[21];

    float* out = (float*)d_out;
    float* o_actions = out;
    float* o_values  = out + N_TOT;
    float* o_logp    = out + 2 * (size_t)N_TOT;
    float* o_hpi     = out + 3 * (size_t)N_TOT;
    float* o_cpi     = o_hpi + NSEQ * 256;
    float* o_hT      = o_cpi + NSEQ * 256;
    float* o_cT      = o_hT  + NSEQ * 256;

    // workspace layout (~88.5 MB total)
    char* ws = (char*)d_ws;
    const size_t MB = 1024 * 1024;
    float* xg_c  = (float*)(ws);                 // 32 MB  (8192 x 1024)
    float* lat_c = (float*)(ws + 32 * MB);       // 32 MB  (8192 x 1024)
    float* hs_c  = (float*)(ws + 64 * MB);       //  8 MB  (8192 x 256)
    float* h1_c  = (float*)(ws + 72 * MB);       // 16 MB  (8192 x 512)
    float* hxc   = (float*)(ws + 88 * MB);                       // 128 KB
    unsigned int* flags = (unsigned int*)(ws + 88 * MB + 131072); // 32 KB
    float* cstate = (float*)(ws + 88 * MB + 131072 + 32768);      // 64 KB

    zero_u32<<<32, 256, 0, stream>>>(flags, NSEQG * TSEQ);

    mask_kernel<<<NSEQ, 256, 0, stream>>>(starts, h_pi, c_pi, o_hpi, o_cpi);

    for (int c = 0; c < NCH; ++c) {
        const int base = c * CS;

        gemm_xg<<<dim3(8, NSEQ), 256, 0, stream>>>(features, W_ih, b_ih, b_hh,
                                                   xg_c, base);
        lstm_chunk<<<NSEQG * NSLICE, 256, 0, stream>>>(
            xg_c, starts, h_vf, c_vf, cstate, W_hh, hs_c, o_hT, o_cT,
            hxc, flags, base);

        gemm_latent<<<dim3(16, NSEQ), 256, 0, stream>>>(
            features, W_feat, W_emb, b_feat, b_emb, lat_c, base);

        gemm_h1p<<<dim3(8, NSEQ), 256, 0, stream>>>(lat_c, Wp1, bp1, h1_c);
        policy_finish<<<1024, 256, 0, stream>>>(h1_c, Wp2, bp2,
                                                o_actions, o_logp, base);

        gemm_h1v<<<dim3(4, NSEQ), 256, 0, stream>>>(lat_c, hs_c, Wv1, bv1, h1_c);
        value_finish<<<128, 256, 0, stream>>>(h1_c, Wv2, bv2, o_values, base);
    }
}

// Round 4
// 25154.436 us; speedup vs baseline: 1.9088x; 1.9088x over previous
//
#include <hip/hip_runtime.h>
#include <stdint.h>
#include <math.h>

#define N_TOT 131072   // NSEQ * T
#define TSEQ  2048
#define NSEQ  64
#define CS    128      // chunk steps
#define NCH   16       // chunks

// ---------------------------------------------------------------------------
// One-time: transpose W_hh (1024x256, row = gate*256+u) into
// Wg[k][u][gate]  (k-major, unit, 4 gates contiguous) for coalesced LSTM loads.
// ---------------------------------------------------------------------------
__global__ __launch_bounds__(256)
void transpose_whh(const float* __restrict__ Whh, float* __restrict__ Wg)
{
    const int k = blockIdx.x;     // 0..255
    const int u = threadIdx.x;    // 0..255
#pragma unroll
    for (int g = 0; g < 4; ++g)
        Wg[(size_t)k * 1024 + u * 4 + g] = Whh[(size_t)(g * 256 + u) * 256 + k];
}

// ---------------------------------------------------------------------------
// gemm_xg (chunk): xg[lr][u*4+g] = feats @ W_ih^T + b_ih + b_hh  (permuted!)
// grid (8, 64): bx = n-tile, by = seq. fp32, 128x128 tile, 8x8 reg block.
// ---------------------------------------------------------------------------
__global__ __launch_bounds__(256)
void gemm_xg(const float* __restrict__ A, const float* __restrict__ Wih,
             const float* __restrict__ bih, const float* __restrict__ bhh,
             float* __restrict__ xg, int base)
{
    __shared__ float As[16][136];
    __shared__ float Bs[16][136];
    const int t  = threadIdx.x;
    const int n0 = blockIdx.x * 128;
    const int seq = blockIdx.y;
    const size_t grow0 = (size_t)seq * TSEQ + base;
    const size_t lrow0 = (size_t)seq * CS;
    const int tx = t & 15, ty = t >> 4;

    float acc[8][8];
#pragma unroll
    for (int i = 0; i < 8; ++i)
#pragma unroll
        for (int j = 0; j < 8; ++j) acc[i][j] = 0.f;

    for (int kt = 0; kt < 256; kt += 16) {
#pragma unroll
        for (int jj = 0; jj < 2; ++jj) {
            int idx = t + 256 * jj;
            int m = idx >> 2, q = idx & 3;
            float4 a = *(const float4*)(A + (grow0 + m) * 256 + kt + q * 4);
            As[q * 4 + 0][m] = a.x; As[q * 4 + 1][m] = a.y;
            As[q * 4 + 2][m] = a.z; As[q * 4 + 3][m] = a.w;
            float4 b = *(const float4*)(Wih + (size_t)(n0 + m) * 256 + kt + q * 4);
            Bs[q * 4 + 0][m] = b.x; Bs[q * 4 + 1][m] = b.y;
            Bs[q * 4 + 2][m] = b.z; Bs[q * 4 + 3][m] = b.w;
        }
        __syncthreads();
#pragma unroll
        for (int k = 0; k < 16; ++k) {
            float4 a0 = *(const float4*)&As[k][ty * 8];
            float4 a1 = *(const float4*)&As[k][ty * 8 + 4];
            float4 b0 = *(const float4*)&Bs[k][tx * 8];
            float4 b1 = *(const float4*)&Bs[k][tx * 8 + 4];
            float av[8] = {a0.x, a0.y, a0.z, a0.w, a1.x, a1.y, a1.z, a1.w};
            float bv[8] = {b0.x, b0.y, b0.z, b0.w, b1.x, b1.y, b1.z, b1.w};
#pragma unroll
            for (int i = 0; i < 8; ++i)
#pragma unroll
                for (int j = 0; j < 8; ++j) acc[i][j] += av[i] * bv[j];
        }
        __syncthreads();
    }
#pragma unroll
    for (int i = 0; i < 8; ++i) {
        size_t lr = lrow0 + ty * 8 + i;
#pragma unroll
        for (int j = 0; j < 8; ++j) {
            int n = n0 + tx * 8 + j;      // gate-major index 0..1023
            int gate = n >> 8, u = n & 255;
            xg[lr * 1024 + u * 4 + gate] = acc[i][j] + bih[n] + bhh[n];
        }
    }
}

// ---------------------------------------------------------------------------
// lstm2: one WG (1024 threads) per sequence. No cross-WG sync.
// Wg streamed from L2 each step. thread (u = t&255, q = t>>8) computes
// quarter-K partial of unit u's 4 gate dots; partials combined in LDS.
// ---------------------------------------------------------------------------
__global__ __launch_bounds__(1024)
void lstm2(const float* __restrict__ xg, const float* __restrict__ starts,
           const float* __restrict__ h0g, const float* __restrict__ c0g,
           float* __restrict__ hstate, float* __restrict__ cstate,
           const float* __restrict__ Wg,
           float* __restrict__ hs, float* __restrict__ hT,
           float* __restrict__ cT, int base)
{
    __shared__ float hvec[256];
    __shared__ float hmask[256];
    __shared__ float part[4][256][4];

    const int t = threadIdx.x;
    const int seq = blockIdx.x;
    const int u = t & 255;
    const int q = t >> 8;

    float c_reg = 0.f;
    if (t < 256) {
        const float* hsrc = (base == 0) ? h0g : hstate;
        const float* csrc = (base == 0) ? c0g : cstate;
        hvec[t] = hsrc[(size_t)seq * 256 + t];
        c_reg   = csrc[(size_t)seq * 256 + t];
    }
    __syncthreads();

    const float* xrow = xg + (size_t)seq * CS * 1024;
    const float* srow = starts + (size_t)seq * TSEQ + base;
    const float* wbase = Wg + (size_t)(q * 64) * 1024 + u * 4;

    for (int lt = 0; lt < CS; ++lt) {
        float m = 1.f - srow[lt];
        if (t < 256) hmask[t] = hvec[t] * m;
        __syncthreads();

        // quarter-K dot: k in [q*64, q*64+64)
        float ax = 0.f, ay = 0.f, az = 0.f, aw = 0.f;
        const float* hp = &hmask[q * 64];
#pragma unroll 4
        for (int k4 = 0; k4 < 16; ++k4) {
            float4 h4 = *(const float4*)(hp + k4 * 4);
            float4 w0 = *(const float4*)(wbase + (size_t)(k4 * 4 + 0) * 1024);
            float4 w1 = *(const float4*)(wbase + (size_t)(k4 * 4 + 1) * 1024);
            float4 w2 = *(const float4*)(wbase + (size_t)(k4 * 4 + 2) * 1024);
            float4 w3 = *(const float4*)(wbase + (size_t)(k4 * 4 + 3) * 1024);
            ax += h4.x * w0.x + h4.y * w1.x + h4.z * w2.x + h4.w * w3.x;
            ay += h4.x * w0.y + h4.y * w1.y + h4.z * w2.y + h4.w * w3.y;
            az += h4.x * w0.z + h4.y * w1.z + h4.z * w2.z + h4.w * w3.z;
            aw += h4.x * w0.w + h4.y * w1.w + h4.z * w2.w + h4.w * w3.w;
        }
        part[q][u][0] = ax; part[q][u][1] = ay;
        part[q][u][2] = az; part[q][u][3] = aw;
        __syncthreads();

        if (t < 256) {
            float4 x4 = *(const float4*)(xrow + (size_t)lt * 1024 + t * 4);
            float gi = part[0][t][0] + part[1][t][0] + part[2][t][0] + part[3][t][0] + x4.x;
            float gf = part[0][t][1] + part[1][t][1] + part[2][t][1] + part[3][t][1] + x4.y;
            float gg = part[0][t][2] + part[1][t][2] + part[2][t][2] + part[3][t][2] + x4.z;
            float go = part[0][t][3] + part[1][t][3] + part[2][t][3] + part[3][t][3] + x4.w;
            float c = c_reg * m;
            float si = 1.f / (1.f + expf(-gi));
            float sf = 1.f / (1.f + expf(-gf));
            float so = 1.f / (1.f + expf(-go));
            c = sf * c + si * tanhf(gg);
            float h = so * tanhf(c);
            c_reg = c;
            hvec[t] = h;
            hs[((size_t)seq * CS + lt) * 256 + t] = h;
            if (lt == CS - 1) {
                cstate[(size_t)seq * 256 + t] = c;
                hstate[(size_t)seq * 256 + t] = h;
            }
            if (base + lt == TSEQ - 1) {
                cT[(size_t)seq * 256 + t] = c;
                hT[(size_t)seq * 256 + t] = h;
            }
        }
        __syncthreads();
    }
}

// ---------------------------------------------------------------------------
// gemm_latent (chunk): lat[lr][n] (n<768: feats@W_feat[0:768]^T + b_feat;
// n>=768: feats@W_emb^T + b_emb). fp64 masters, 64x64 tile, 4x4/thread.
// grid (16, 128): bx = 64-col tile, by = 64-row tile.
// ---------------------------------------------------------------------------
__global__ __launch_bounds__(256)
void gemm_latent(const float* __restrict__ A, const float* __restrict__ Wfeat,
                 const float* __restrict__ Wemb, const float* __restrict__ bfeat,
                 const float* __restrict__ bemb, float* __restrict__ lat, int base)
{
    __shared__ float As[16][72];
    __shared__ float Bs[16][72];
    const int t  = threadIdx.x;
    const int n0 = blockIdx.x * 64;
    const size_t lr0 = (size_t)blockIdx.y * 64;
    const size_t grow0 = (lr0 >> 7) * TSEQ + base + (lr0 & 127);
    const int tx = t & 15, ty = t >> 4;

    double acc[4][4];
#pragma unroll
    for (int i = 0; i < 4; ++i)
#pragma unroll
        for (int j = 0; j < 4; ++j) acc[i][j] = 0.0;

    for (int kt = 0; kt < 256; kt += 16) {
        {
            int m = t >> 2, q = t & 3;
            float4 a = *(const float4*)(A + (grow0 + m) * 256 + kt + q * 4);
            As[q * 4 + 0][m] = a.x; As[q * 4 + 1][m] = a.y;
            As[q * 4 + 2][m] = a.z; As[q * 4 + 3][m] = a.w;
            int n = n0 + m;
            const float* Brow = (n < 768) ? (Wfeat + (size_t)n * 256)
                                          : (Wemb + (size_t)(n - 768) * 256);
            float4 b = *(const float4*)(Brow + kt + q * 4);
            Bs[q * 4 + 0][m] = b.x; Bs[q * 4 + 1][m] = b.y;
            Bs[q * 4 + 2][m] = b.z; Bs[q * 4 + 3][m] = b.w;
        }
        __syncthreads();
        float p[4][4];
#pragma unroll
        for (int i = 0; i < 4; ++i)
#pragma unroll
            for (int j = 0; j < 4; ++j) p[i][j] = 0.f;
#pragma unroll
        for (int k = 0; k < 16; ++k) {
            float4 a0 = *(const float4*)&As[k][ty * 4];
            float4 b0 = *(const float4*)&Bs[k][tx * 4];
            float av[4] = {a0.x, a0.y, a0.z, a0.w};
            float bv[4] = {b0.x, b0.y, b0.z, b0.w};
#pragma unroll
            for (int i = 0; i < 4; ++i)
#pragma unroll
                for (int j = 0; j < 4; ++j) p[i][j] += av[i] * bv[j];
        }
#pragma unroll
        for (int i = 0; i < 4; ++i)
#pragma unroll
            for (int j = 0; j < 4; ++j) acc[i][j] += (double)p[i][j];
        __syncthreads();
    }
#pragma unroll
    for (int i = 0; i < 4; ++i) {
        size_t lr = lr0 + ty * 4 + i;
#pragma unroll
        for (int j = 0; j < 4; ++j) {
            int n = n0 + tx * 4 + j;
            float v = (float)acc[i][j];
            v += (n < 768) ? bfeat[n] : bemb[n - 768];
            lat[lr * 1024 + n] = v;
        }
    }
}

// ---------------------------------------------------------------------------
// gemm_h1p (chunk): h1[lr][n] = relu(lat[lr] @ Wp1[n]^T + bp1[n]), K=1024.
// fp64 masters, 64x64 tile, 4x4/thread. grid (8, 128).
// ---------------------------------------------------------------------------
__global__ __launch_bounds__(256)
void gemm_h1p(const float* __restrict__ lat, const float* __restrict__ Wp1,
              const float* __restrict__ bp1, float* __restrict__ h1)
{
    __shared__ float As[16][72];
    __shared__ float Bs[16][72];
    const int t  = threadIdx.x;
    const int n0 = blockIdx.x * 64;
    const size_t lr0 = (size_t)blockIdx.y * 64;
    const int tx = t & 15, ty = t >> 4;

    double acc[4][4];
#pragma unroll
    for (int i = 0; i < 4; ++i)
#pragma unroll
        for (int j = 0; j < 4; ++j) acc[i][j] = 0.0;

    for (int kt = 0; kt < 1024; kt += 16) {
        {
            int m = t >> 2, q = t & 3;
            float4 a = *(const float4*)(lat + (lr0 + m) * 1024 + kt + q * 4);
            As[q * 4 + 0][m] = a.x; As[q * 4 + 1][m] = a.y;
            As[q * 4 + 2][m] = a.z; As[q * 4 + 3][m] = a.w;
            float4 b = *(const float4*)(Wp1 + (size_t)(n0 + m) * 1024 + kt + q * 4);
            Bs[q * 4 + 0][m] = b.x; Bs[q * 4 + 1][m] = b.y;
            Bs[q * 4 + 2][m] = b.z; Bs[q * 4 + 3][m] = b.w;
        }
        __syncthreads();
        float p[4][4];
#pragma unroll
        for (int i = 0; i < 4; ++i)
#pragma unroll
            for (int j = 0; j < 4; ++j) p[i][j] = 0.f;
#pragma unroll
        for (int k = 0; k < 16; ++k) {
            float4 a0 = *(const float4*)&As[k][ty * 4];
            float4 b0 = *(const float4*)&Bs[k][tx * 4];
            float av[4] = {a0.x, a0.y, a0.z, a0.w};
            float bv[4] = {b0.x, b0.y, b0.z, b0.w};
#pragma unroll
            for (int i = 0; i < 4; ++i)
#pragma unroll
                for (int j = 0; j < 4; ++j) p[i][j] += av[i] * bv[j];
        }
#pragma unroll
        for (int i = 0; i < 4; ++i)
#pragma unroll
            for (int j = 0; j < 4; ++j) acc[i][j] += (double)p[i][j];
        __syncthreads();
    }
#pragma unroll
    for (int i = 0; i < 4; ++i) {
        size_t lr = lr0 + ty * 4 + i;
#pragma unroll
        for (int j = 0; j < 4; ++j) {
            int n = n0 + tx * 4 + j;
            float v = (float)acc[i][j] + bp1[n];
            h1[lr * 512 + n] = v > 0.f ? v : 0.f;
        }
    }
}

// ---------------------------------------------------------------------------
// gemm_h1v (chunk): h1[lr][n] = relu(lat[lr][0:768]@Wv1[n][0:768]^T
//                                  + hs[lr]@Wv1[n][768:]^T + bv1[n])  fp32
// grid (4, 64): 128x128 tile, 8x8/thread.
// ---------------------------------------------------------------------------
__global__ __launch_bounds__(256)
void gemm_h1v(const float* __restrict__ lat, const float* __restrict__ hs,
              const float* __restrict__ Wv1, const float* __restrict__ bv1,
              float* __restrict__ h1)
{
    __shared__ float As[16][136];
    __shared__ float Bs[16][136];
    const int t  = threadIdx.x;
    const int n0 = blockIdx.x * 128;
    const size_t lrow0 = (size_t)blockIdx.y * 128;
    const int tx = t & 15, ty = t >> 4;

    float acc[8][8];
#pragma unroll
    for (int i = 0; i < 8; ++i)
#pragma unroll
        for (int j = 0; j < 8; ++j) acc[i][j] = 0.f;

    for (int pass = 0; pass < 2; ++pass) {
        const float* A  = (pass == 0) ? lat : hs;
        const int lda   = (pass == 0) ? 1024 : 256;
        const int kmax  = (pass == 0) ? 768 : 256;
        const int boff  = (pass == 0) ? 0 : 768;
        for (int kt = 0; kt < kmax; kt += 16) {
#pragma unroll
            for (int jj = 0; jj < 2; ++jj) {
                int idx = t + 256 * jj;
                int m = idx >> 2, q = idx & 3;
                float4 a = *(const float4*)(A + (lrow0 + m) * lda + kt + q * 4);
                As[q * 4 + 0][m] = a.x; As[q * 4 + 1][m] = a.y;
                As[q * 4 + 2][m] = a.z; As[q * 4 + 3][m] = a.w;
                float4 b = *(const float4*)(Wv1 + (size_t)(n0 + m) * 1024 + boff + kt + q * 4);
                Bs[q * 4 + 0][m] = b.x; Bs[q * 4 + 1][m] = b.y;
                Bs[q * 4 + 2][m] = b.z; Bs[q * 4 + 3][m] = b.w;
            }
            __syncthreads();
#pragma unroll
            for (int k = 0; k < 16; ++k) {
                float4 a0 = *(const float4*)&As[k][ty * 8];
                float4 a1 = *(const float4*)&As[k][ty * 8 + 4];
                float4 b0 = *(const float4*)&Bs[k][tx * 8];
                float4 b1 = *(const float4*)&Bs[k][tx * 8 + 4];
                float av[8] = {a0.x, a0.y, a0.z, a0.w, a1.x, a1.y, a1.z, a1.w};
                float bv[8] = {b0.x, b0.y, b0.z, b0.w, b1.x, b1.y, b1.z, b1.w};
#pragma unroll
                for (int i = 0; i < 8; ++i)
#pragma unroll
                    for (int j = 0; j < 8; ++j) acc[i][j] += av[i] * bv[j];
            }
            __syncthreads();
        }
    }
#pragma unroll
    for (int i = 0; i < 8; ++i) {
        size_t lr = lrow0 + ty * 8 + i;
#pragma unroll
        for (int j = 0; j < 8; ++j) {
            int n = n0 + tx * 8 + j;
            float v = acc[i][j] + bv1[n];
            h1[lr * 512 + n] = v > 0.f ? v : 0.f;
        }
    }
}

// ---------------------------------------------------------------------------
__global__ __launch_bounds__(256)
void mask_kernel(const float* __restrict__ starts, const float* __restrict__ h_pi,
                 const float* __restrict__ c_pi,
                 float* __restrict__ o_hpi, float* __restrict__ o_cpi)
{
    __shared__ float red[256];
    const int n = blockIdx.x, t = threadIdx.x;
    float a = 0.f;
    for (int j = 0; j < 8; ++j)
        a = fmaxf(a, starts[(size_t)n * TSEQ + t * 8 + j]);
    red[t] = a; __syncthreads();
    for (int s = 128; s > 0; s >>= 1) {
        if (t < s) red[t] = fmaxf(red[t], red[t + s]);
        __syncthreads();
    }
    float m = (red[0] > 0.f) ? 0.f : 1.f;
    o_hpi[(size_t)n * 256 + t] = h_pi[(size_t)n * 256 + t] * m;
    o_cpi[(size_t)n * 256 + t] = c_pi[(size_t)n * 256 + t] * m;
}

// ---------------------------------------------------------------------------
// policy_finish (chunk): logits (fp64 dot) -> argmax, log-softmax pick.
// 8 rows x 32 lanes per block; 1024 blocks/chunk.
// ---------------------------------------------------------------------------
__global__ __launch_bounds__(256)
void policy_finish(const float* __restrict__ h1p, const float* __restrict__ Wp2,
                   const float* __restrict__ bp2,
                   float* __restrict__ o_actions, float* __restrict__ o_logp,
                   int base)
{
    __shared__ float w2t[512 * 32];   // [k][c]
    const int t = threadIdx.x;
    for (int j = 0; j < 64; ++j) {
        int idx = t + 256 * j;
        int k = idx >> 5, c = idx & 31;
        w2t[idx] = Wp2[(size_t)c * 512 + k];
    }
    __syncthreads();

    const int c = t & 31;
    size_t lr = (size_t)blockIdx.x * 8 + (t >> 5);
    size_t grow = (lr >> 7) * TSEQ + base + (lr & 127);
    const float* hrow = h1p + lr * 512;
    double s = 0.0;
    for (int k = 0; k < 512; k += 4) {
        float4 h4 = *(const float4*)(hrow + k);
        s += (double)h4.x * (double)w2t[(k + 0) * 32 + c];
        s += (double)h4.y * (double)w2t[(k + 1) * 32 + c];
        s += (double)h4.z * (double)w2t[(k + 2) * 32 + c];
        s += (double)h4.w * (double)w2t[(k + 3) * 32 + c];
    }
    double logit = s + (double)bp2[c];

    double mv = logit; int mi = c;
#pragma unroll
    for (int off = 16; off >= 1; off >>= 1) {
        double ov = __shfl_xor(mv, off, 32);
        int    oi = __shfl_xor(mi, off, 32);
        if (ov > mv || (ov == mv && oi < mi)) { mv = ov; mi = oi; }
    }
    double se = exp(logit - mv);
#pragma unroll
    for (int off = 16; off >= 1; off >>= 1) se += __shfl_xor(se, off, 32);

    if (c == 0) {
        o_actions[grow] = (float)mi;
        o_logp[grow]    = (float)(-log(se));
    }
}

// ---------------------------------------------------------------------------
// value_finish (chunk): values = h1v . Wv2 + bv2. 64 rows x 4 lanes; 128 blocks.
// ---------------------------------------------------------------------------
__global__ __launch_bounds__(256)
void value_finish(const float* __restrict__ h1v, const float* __restrict__ Wv2,
                  const float* __restrict__ bv2, float* __restrict__ o_values,
                  int base)
{
    __shared__ float wv[512];
    const int t = threadIdx.x;
    wv[t] = Wv2[t]; wv[t + 256] = Wv2[t + 256];
    __syncthreads();
    const int q = t & 3;
    size_t lr = (size_t)blockIdx.x * 64 + (t >> 2);
    size_t grow = (lr >> 7) * TSEQ + base + (lr & 127);
    const float* hrow = h1v + lr * 512;
    float s = 0.f;
    for (int k = q * 128; k < q * 128 + 128; k += 4) {
        float4 h4 = *(const float4*)(hrow + k);
        float4 w4 = *(const float4*)&wv[k];
        s += h4.x * w4.x + h4.y * w4.y + h4.z * w4.z + h4.w * w4.w;
    }
    s += __shfl_xor(s, 1, 4);
    s += __shfl_xor(s, 2, 4);
    if (q == 0) o_values[grow] = s + bv2[0];
}

// ---------------------------------------------------------------------------
extern "C" void kernel_launch(void* const* d_in, const int* in_sizes, int n_in,
                              void* d_out, int out_size, void* d_ws, size_t ws_size,
                              hipStream_t stream)
{
    const float* features = (const float*)d_in[0];
    const float* starts   = (const float*)d_in[1];
    const float* h_pi     = (const float*)d_in[2];
    const float* c_pi     = (const float*)d_in[3];
    const float* h_vf     = (const float*)d_in[4];
    const float* c_vf     = (const float*)d_in[5];
    const float* W_feat   = (const float*)d_in[6];
    const float* b_feat   = (const float*)d_in[7];
    const float* W_emb    = (const float*)d_in[8];
    const float* b_emb    = (const float*)d_in[9];
    const float* W_ih     = (const float*)d_in[10];
    const float* W_hh     = (const float*)d_in[11];
    const float* b_ih     = (const float*)d_in[12];
    const float* b_hh     = (const float*)d_in[13];
    const float* Wp1      = (const float*)d_in[14];
    const float* bp1      = (const float*)d_in[15];
    const float* Wp2      = (const float*)d_in[16];
    const float* bp2      = (const float*)d_in[17];
    const float* Wv1      = (const float*)d_in[18];
    const float* bv1      = (const float*)d_in[19];
    const float* Wv2      = (const float*)d_in[20];
    const float* bv2      = (const float*)d_in[21];

    float* out = (float*)d_out;
    float* o_actions = out;
    float* o_values  = out + N_TOT;
    float* o_logp    = out + 2 * (size_t)N_TOT;
    float* o_hpi     = out + 3 * (size_t)N_TOT;
    float* o_cpi     = o_hpi + NSEQ * 256;
    float* o_hT      = o_cpi + NSEQ * 256;
    float* o_cT      = o_hT  + NSEQ * 256;

    // workspace (~89.3 MB)
    char* ws = (char*)d_ws;
    const size_t MB = 1024 * 1024;
    float* xg_c  = (float*)(ws);                 // 32 MB  (8192 x 1024)
    float* lat_c = (float*)(ws + 32 * MB);       // 32 MB  (8192 x 1024)
    float* hs_c  = (float*)(ws + 64 * MB);       //  8 MB  (8192 x 256)
    float* h1_c  = (float*)(ws + 72 * MB);       // 16 MB  (8192 x 512)
    float* Wg    = (float*)(ws + 88 * MB);       //  1 MB  (256 x 256 x 4)
    float* hstate = (float*)(ws + 89 * MB);              // 64 KB
    float* cstate = (float*)(ws + 89 * MB + 65536);      // 64 KB

    transpose_whh<<<256, 256, 0, stream>>>(W_hh, Wg);

    mask_kernel<<<NSEQ, 256, 0, stream>>>(starts, h_pi, c_pi, o_hpi, o_cpi);

    for (int c = 0; c < NCH; ++c) {
        const int base = c * CS;

        gemm_xg<<<dim3(8, NSEQ), 256, 0, stream>>>(features, W_ih, b_ih, b_hh,
                                                   xg_c, base);
        lstm2<<<NSEQ, 1024, 0, stream>>>(xg_c, starts, h_vf, c_vf,
                                         hstate, cstate, Wg,
                                         hs_c, o_hT, o_cT, base);

        gemm_latent<<<dim3(16, 128), 256, 0, stream>>>(
            features, W_feat, W_emb, b_feat, b_emb, lat_c, base);

        gemm_h1p<<<dim3(8, 128), 256, 0, stream>>>(lat_c, Wp1, bp1, h1_c);
        policy_finish<<<1024, 256, 0, stream>>>(h1_c, Wp2, bp2,
                                                o_actions, o_logp, base);

        gemm_h1v<<<dim3(4, 64), 256, 0, stream>>>(lat_c, hs_c, Wv1, bv1, h1_c);
        value_finish<<<128, 256, 0, stream>>>(h1_c, Wv2, bv2, o_values, base);
    }
}

// Round 5
// 23335.071 us; speedup vs baseline: 2.0576x; 1.0780x over previous
//
#include <hip/hip_runtime.h>
#include <stdint.h>
#include <math.h>

#define N_TOT 131072   // NSEQ * T
#define TSEQ  2048
#define NSEQ  64
#define CS    128      // chunk steps
#define NCH   16       // chunks
#define PARTS 4        // WGs per sequence

// ---------------------------------------------------------------------------
__global__ __launch_bounds__(256)
void zero_u32(unsigned int* __restrict__ p, int n)
{
    int i = blockIdx.x * 256 + threadIdx.x;
    if (i < n) p[i] = 0u;
}

// ---------------------------------------------------------------------------
// One-time: transpose W_hh (1024x256, row = gate*256+u) into
// Wg[k][u][gate]  (k-major, unit, 4 gates contiguous).
// ---------------------------------------------------------------------------
__global__ __launch_bounds__(256)
void transpose_whh(const float* __restrict__ Whh, float* __restrict__ Wg)
{
    const int k = blockIdx.x;     // 0..255
    const int u = threadIdx.x;    // 0..255
#pragma unroll
    for (int g = 0; g < 4; ++g)
        Wg[(size_t)k * 1024 + u * 4 + g] = Whh[(size_t)(g * 256 + u) * 256 + k];
}

// ---------------------------------------------------------------------------
// gemm_xg (chunk): xg[lr][u*4+g] = feats @ W_ih^T + b_ih + b_hh  (permuted)
// grid (8, 64): bx = n-tile, by = seq. fp32, 128x128 tile, 8x8 reg block.
// ---------------------------------------------------------------------------
__global__ __launch_bounds__(256)
void gemm_xg(const float* __restrict__ A, const float* __restrict__ Wih,
             const float* __restrict__ bih, const float* __restrict__ bhh,
             float* __restrict__ xg, int base)
{
    __shared__ float As[16][136];
    __shared__ float Bs[16][136];
    const int t  = threadIdx.x;
    const int n0 = blockIdx.x * 128;
    const int seq = blockIdx.y;
    const size_t grow0 = (size_t)seq * TSEQ + base;
    const size_t lrow0 = (size_t)seq * CS;
    const int tx = t & 15, ty = t >> 4;

    float acc[8][8];
#pragma unroll
    for (int i = 0; i < 8; ++i)
#pragma unroll
        for (int j = 0; j < 8; ++j) acc[i][j] = 0.f;

    for (int kt = 0; kt < 256; kt += 16) {
#pragma unroll
        for (int jj = 0; jj < 2; ++jj) {
            int idx = t + 256 * jj;
            int m = idx >> 2, q = idx & 3;
            float4 a = *(const float4*)(A + (grow0 + m) * 256 + kt + q * 4);
            As[q * 4 + 0][m] = a.x; As[q * 4 + 1][m] = a.y;
            As[q * 4 + 2][m] = a.z; As[q * 4 + 3][m] = a.w;
            float4 b = *(const float4*)(Wih + (size_t)(n0 + m) * 256 + kt + q * 4);
            Bs[q * 4 + 0][m] = b.x; Bs[q * 4 + 1][m] = b.y;
            Bs[q * 4 + 2][m] = b.z; Bs[q * 4 + 3][m] = b.w;
        }
        __syncthreads();
#pragma unroll
        for (int k = 0; k < 16; ++k) {
            float4 a0 = *(const float4*)&As[k][ty * 8];
            float4 a1 = *(const float4*)&As[k][ty * 8 + 4];
            float4 b0 = *(const float4*)&Bs[k][tx * 8];
            float4 b1 = *(const float4*)&Bs[k][tx * 8 + 4];
            float av[8] = {a0.x, a0.y, a0.z, a0.w, a1.x, a1.y, a1.z, a1.w};
            float bv[8] = {b0.x, b0.y, b0.z, b0.w, b1.x, b1.y, b1.z, b1.w};
#pragma unroll
            for (int i = 0; i < 8; ++i)
#pragma unroll
                for (int j = 0; j < 8; ++j) acc[i][j] += av[i] * bv[j];
        }
        __syncthreads();
    }
#pragma unroll
    for (int i = 0; i < 8; ++i) {
        size_t lr = lrow0 + ty * 8 + i;
#pragma unroll
        for (int j = 0; j < 8; ++j) {
            int n = n0 + tx * 8 + j;      // gate-major index 0..1023
            int gate = n >> 8, u = n & 255;
            xg[lr * 1024 + u * 4 + gate] = acc[i][j] + bih[n] + bhh[n];
        }
    }
}

// ---------------------------------------------------------------------------
// lstm3: register-resident weights. 256 WGs = 64 seqs x 4 parts (64 units).
// Thread (u = t&63, q = t>>6) holds W slice [k in q*16..q*16+16) x 4 gates]
// = 16 float4 in VGPRs. Cross-WG h exchange via agent-scope atomics to a
// double-buffered global hx + per-step flag counters (4 writers each).
// ---------------------------------------------------------------------------
__global__ __launch_bounds__(1024)
void lstm3(const float* __restrict__ xg, const float* __restrict__ starts,
           const float* __restrict__ h0g, const float* __restrict__ c0g,
           float* __restrict__ hstate, float* __restrict__ cstate,
           const float* __restrict__ Wg,
           float* __restrict__ hs, float* __restrict__ hT,
           float* __restrict__ cT,
           float* __restrict__ hx, unsigned int* __restrict__ flags, int base)
{
    __shared__ float hmask[256];
    __shared__ float part[16][64][4];   // 16 KB
    __shared__ float gsum[64][4];

    const int t   = threadIdx.x;
    const int seq = blockIdx.x >> 2;
    const int p   = blockIdx.x & 3;
    const int u   = t & 63;
    const int q   = t >> 6;            // 0..15

    // weights into registers: 16 float4 (64 VGPRs)
    float4 Wr[16];
#pragma unroll
    for (int kk = 0; kk < 16; ++kk)
        Wr[kk] = *(const float4*)(Wg + (size_t)(q * 16 + kk) * 1024 + (p * 64 + u) * 4);

    float c_reg = 0.f;
    if (t < 64) {
        const float* csrc = (base == 0) ? c0g : cstate;
        c_reg = csrc[(size_t)seq * 256 + p * 64 + t];
    }

    unsigned int* flg = flags + (size_t)seq * TSEQ;

    for (int lt = 0; lt < CS; ++lt) {
        const int S = base + lt;
        const float m = 1.f - starts[(size_t)seq * TSEQ + S];

        if (lt == 0) {
            if (t < 256) {
                const float* hsrc = (base == 0) ? h0g : hstate;
                hmask[t] = hsrc[(size_t)seq * 256 + t] * m;
            }
        } else {
            if (t == 0) {
                unsigned spins = 0;
                while (__hip_atomic_load(&flg[S - 1], __ATOMIC_ACQUIRE,
                                         __HIP_MEMORY_SCOPE_AGENT) < (unsigned)PARTS) {
                    __builtin_amdgcn_s_sleep(4);
                    if (++spins > (1u << 17)) break;   // safety valve
                }
            }
            __syncthreads();
            if (t < 256) {
                float v = __hip_atomic_load(
                    &hx[(size_t)(S & 1) * (NSEQ * 256) + (size_t)seq * 256 + t],
                    __ATOMIC_RELAXED, __HIP_MEMORY_SCOPE_AGENT);
                hmask[t] = v * m;
            }
        }
        __syncthreads();

        // partial dot over k in [q*16, q*16+16) for unit u, 4 gates
        const float* hp = &hmask[q * 16];
        float4 h0 = *(const float4*)(hp + 0);
        float4 h1 = *(const float4*)(hp + 4);
        float4 h2 = *(const float4*)(hp + 8);
        float4 h3 = *(const float4*)(hp + 12);
        float hv[16] = {h0.x,h0.y,h0.z,h0.w, h1.x,h1.y,h1.z,h1.w,
                        h2.x,h2.y,h2.z,h2.w, h3.x,h3.y,h3.z,h3.w};
        float a0 = 0.f, a1 = 0.f, a2 = 0.f, a3 = 0.f;
#pragma unroll
        for (int kk = 0; kk < 16; ++kk) {
            a0 += hv[kk] * Wr[kk].x;
            a1 += hv[kk] * Wr[kk].y;
            a2 += hv[kk] * Wr[kk].z;
            a3 += hv[kk] * Wr[kk].w;
        }
        part[q][u][0] = a0; part[q][u][1] = a1;
        part[q][u][2] = a2; part[q][u][3] = a3;
        __syncthreads();

        if (t < 256) {
            int uu = t >> 2, g = t & 3;
            float s = 0.f;
#pragma unroll
            for (int qq = 0; qq < 16; ++qq) s += part[qq][uu][g];
            gsum[uu][g] = s;
        }
        __syncthreads();

        if (t < 64) {
            const int gu = p * 64 + t;
            float4 gs = *(const float4*)&gsum[t][0];
            float4 x4 = *(const float4*)(xg + ((size_t)seq * CS + lt) * 1024 + gu * 4);
            float gi = gs.x + x4.x;
            float gf = gs.y + x4.y;
            float gg = gs.z + x4.z;
            float go = gs.w + x4.w;
            float c = c_reg * m;
            float si = 1.f / (1.f + expf(-gi));
            float sf = 1.f / (1.f + expf(-gf));
            float so = 1.f / (1.f + expf(-go));
            c = sf * c + si * tanhf(gg);
            float h = so * tanhf(c);
            c_reg = c;
            __hip_atomic_store(
                &hx[(size_t)((S + 1) & 1) * (NSEQ * 256) + (size_t)seq * 256 + gu],
                h, __ATOMIC_RELAXED, __HIP_MEMORY_SCOPE_AGENT);
            hs[((size_t)seq * CS + lt) * 256 + gu] = h;
            if (lt == CS - 1) {
                cstate[(size_t)seq * 256 + gu] = c;
                hstate[(size_t)seq * 256 + gu] = h;
            }
            if (S == TSEQ - 1) {
                cT[(size_t)seq * 256 + gu] = c;
                hT[(size_t)seq * 256 + gu] = h;
            }
        }
        __syncthreads();
        if (t == 0)
            __hip_atomic_fetch_add(&flg[S], 1u, __ATOMIC_RELEASE,
                                   __HIP_MEMORY_SCOPE_AGENT);
    }
}

// ---------------------------------------------------------------------------
// gemm_latent (chunk): lat[lr][n] (n<768: feats@W_feat^T + b_feat;
// n>=768: feats@W_emb^T + b_emb). fp64 masters, 64x64 tile, 4x4/thread.
// ---------------------------------------------------------------------------
__global__ __launch_bounds__(256)
void gemm_latent(const float* __restrict__ A, const float* __restrict__ Wfeat,
                 const float* __restrict__ Wemb, const float* __restrict__ bfeat,
                 const float* __restrict__ bemb, float* __restrict__ lat, int base)
{
    __shared__ float As[16][72];
    __shared__ float Bs[16][72];
    const int t  = threadIdx.x;
    const int n0 = blockIdx.x * 64;
    const size_t lr0 = (size_t)blockIdx.y * 64;
    const size_t grow0 = (lr0 >> 7) * TSEQ + base + (lr0 & 127);
    const int tx = t & 15, ty = t >> 4;

    double acc[4][4];
#pragma unroll
    for (int i = 0; i < 4; ++i)
#pragma unroll
        for (int j = 0; j < 4; ++j) acc[i][j] = 0.0;

    for (int kt = 0; kt < 256; kt += 16) {
        {
            int m = t >> 2, q = t & 3;
            float4 a = *(const float4*)(A + (grow0 + m) * 256 + kt + q * 4);
            As[q * 4 + 0][m] = a.x; As[q * 4 + 1][m] = a.y;
            As[q * 4 + 2][m] = a.z; As[q * 4 + 3][m] = a.w;
            int n = n0 + m;
            const float* Brow = (n < 768) ? (Wfeat + (size_t)n * 256)
                                          : (Wemb + (size_t)(n - 768) * 256);
            float4 b = *(const float4*)(Brow + kt + q * 4);
            Bs[q * 4 + 0][m] = b.x; Bs[q * 4 + 1][m] = b.y;
            Bs[q * 4 + 2][m] = b.z; Bs[q * 4 + 3][m] = b.w;
        }
        __syncthreads();
        float p[4][4];
#pragma unroll
        for (int i = 0; i < 4; ++i)
#pragma unroll
            for (int j = 0; j < 4; ++j) p[i][j] = 0.f;
#pragma unroll
        for (int k = 0; k < 16; ++k) {
            float4 a0 = *(const float4*)&As[k][ty * 4];
            float4 b0 = *(const float4*)&Bs[k][tx * 4];
            float av[4] = {a0.x, a0.y, a0.z, a0.w};
            float bv[4] = {b0.x, b0.y, b0.z, b0.w};
#pragma unroll
            for (int i = 0; i < 4; ++i)
#pragma unroll
                for (int j = 0; j < 4; ++j) p[i][j] += av[i] * bv[j];
        }
#pragma unroll
        for (int i = 0; i < 4; ++i)
#pragma unroll
            for (int j = 0; j < 4; ++j) acc[i][j] += (double)p[i][j];
        __syncthreads();
    }
#pragma unroll
    for (int i = 0; i < 4; ++i) {
        size_t lr = lr0 + ty * 4 + i;
#pragma unroll
        for (int j = 0; j < 4; ++j) {
            int n = n0 + tx * 4 + j;
            float v = (float)acc[i][j];
            v += (n < 768) ? bfeat[n] : bemb[n - 768];
            lat[lr * 1024 + n] = v;
        }
    }
}

// ---------------------------------------------------------------------------
// gemm_h1p (chunk): h1[lr][n] = relu(lat[lr] @ Wp1[n]^T + bp1[n]), K=1024.
// fp64 masters, 64x64 tile, 4x4/thread. grid (8, 128).
// ---------------------------------------------------------------------------
__global__ __launch_bounds__(256)
void gemm_h1p(const float* __restrict__ lat, const float* __restrict__ Wp1,
              const float* __restrict__ bp1, float* __restrict__ h1)
{
    __shared__ float As[16][72];
    __shared__ float Bs[16][72];
    const int t  = threadIdx.x;
    const int n0 = blockIdx.x * 64;
    const size_t lr0 = (size_t)blockIdx.y * 64;
    const int tx = t & 15, ty = t >> 4;

    double acc[4][4];
#pragma unroll
    for (int i = 0; i < 4; ++i)
#pragma unroll
        for (int j = 0; j < 4; ++j) acc[i][j] = 0.0;

    for (int kt = 0; kt < 1024; kt += 16) {
        {
            int m = t >> 2, q = t & 3;
            float4 a = *(const float4*)(lat + (lr0 + m) * 1024 + kt + q * 4);
            As[q * 4 + 0][m] = a.x; As[q * 4 + 1][m] = a.y;
            As[q * 4 + 2][m] = a.z; As[q * 4 + 3][m] = a.w;
            float4 b = *(const float4*)(Wp1 + (size_t)(n0 + m) * 1024 + kt + q * 4);
            Bs[q * 4 + 0][m] = b.x; Bs[q * 4 + 1][m] = b.y;
            Bs[q * 4 + 2][m] = b.z; Bs[q * 4 + 3][m] = b.w;
        }
        __syncthreads();
        float p[4][4];
#pragma unroll
        for (int i = 0; i < 4; ++i)
#pragma unroll
            for (int j = 0; j < 4; ++j) p[i][j] = 0.f;
#pragma unroll
        for (int k = 0; k < 16; ++k) {
            float4 a0 = *(const float4*)&As[k][ty * 4];
            float4 b0 = *(const float4*)&Bs[k][tx * 4];
            float av[4] = {a0.x, a0.y, a0.z, a0.w};
            float bv[4] = {b0.x, b0.y, b0.z, b0.w};
#pragma unroll
            for (int i = 0; i < 4; ++i)
#pragma unroll
                for (int j = 0; j < 4; ++j) p[i][j] += av[i] * bv[j];
        }
#pragma unroll
        for (int i = 0; i < 4; ++i)
#pragma unroll
            for (int j = 0; j < 4; ++j) acc[i][j] += (double)p[i][j];
        __syncthreads();
    }
#pragma unroll
    for (int i = 0; i < 4; ++i) {
        size_t lr = lr0 + ty * 4 + i;
#pragma unroll
        for (int j = 0; j < 4; ++j) {
            int n = n0 + tx * 4 + j;
            float v = (float)acc[i][j] + bp1[n];
            h1[lr * 512 + n] = v > 0.f ? v : 0.f;
        }
    }
}

// ---------------------------------------------------------------------------
// gemm_h1v (chunk): h1[lr][n] = relu(lat[lr][0:768]@Wv1[n][0:768]^T
//                                  + hs[lr]@Wv1[n][768:]^T + bv1[n])  fp32
// grid (4, 64): 128x128 tile, 8x8/thread.
// ---------------------------------------------------------------------------
__global__ __launch_bounds__(256)
void gemm_h1v(const float* __restrict__ lat, const float* __restrict__ hs,
              const float* __restrict__ Wv1, const float* __restrict__ bv1,
              float* __restrict__ h1)
{
    __shared__ float As[16][136];
    __shared__ float Bs[16][136];
    const int t  = threadIdx.x;
    const int n0 = blockIdx.x * 128;
    const size_t lrow0 = (size_t)blockIdx.y * 128;
    const int tx = t & 15, ty = t >> 4;

    float acc[8][8];
#pragma unroll
    for (int i = 0; i < 8; ++i)
#pragma unroll
        for (int j = 0; j < 8; ++j) acc[i][j] = 0.f;

    for (int pass = 0; pass < 2; ++pass) {
        const float* A  = (pass == 0) ? lat : hs;
        const int lda   = (pass == 0) ? 1024 : 256;
        const int kmax  = (pass == 0) ? 768 : 256;
        const int boff  = (pass == 0) ? 0 : 768;
        for (int kt = 0; kt < kmax; kt += 16) {
#pragma unroll
            for (int jj = 0; jj < 2; ++jj) {
                int idx = t + 256 * jj;
                int m = idx >> 2, q = idx & 3;
                float4 a = *(const float4*)(A + (lrow0 + m) * lda + kt + q * 4);
                As[q * 4 + 0][m] = a.x; As[q * 4 + 1][m] = a.y;
                As[q * 4 + 2][m] = a.z; As[q * 4 + 3][m] = a.w;
                float4 b = *(const float4*)(Wv1 + (size_t)(n0 + m) * 1024 + boff + kt + q * 4);
                Bs[q * 4 + 0][m] = b.x; Bs[q * 4 + 1][m] = b.y;
                Bs[q * 4 + 2][m] = b.z; Bs[q * 4 + 3][m] = b.w;
            }
            __syncthreads();
#pragma unroll
            for (int k = 0; k < 16; ++k) {
                float4 a0 = *(const float4*)&As[k][ty * 8];
                float4 a1 = *(const float4*)&As[k][ty * 8 + 4];
                float4 b0 = *(const float4*)&Bs[k][tx * 8];
                float4 b1 = *(const float4*)&Bs[k][tx * 8 + 4];
                float av[8] = {a0.x, a0.y, a0.z, a0.w, a1.x, a1.y, a1.z, a1.w};
                float bv[8] = {b0.x, b0.y, b0.z, b0.w, b1.x, b1.y, b1.z, b1.w};
#pragma unroll
                for (int i = 0; i < 8; ++i)
#pragma unroll
                    for (int j = 0; j < 8; ++j) acc[i][j] += av[i] * bv[j];
            }
            __syncthreads();
        }
    }
#pragma unroll
    for (int i = 0; i < 8; ++i) {
        size_t lr = lrow0 + ty * 8 + i;
#pragma unroll
        for (int j = 0; j < 8; ++j) {
            int n = n0 + tx * 8 + j;
            float v = acc[i][j] + bv1[n];
            h1[lr * 512 + n] = v > 0.f ? v : 0.f;
        }
    }
}

// ---------------------------------------------------------------------------
__global__ __launch_bounds__(256)
void mask_kernel(const float* __restrict__ starts, const float* __restrict__ h_pi,
                 const float* __restrict__ c_pi,
                 float* __restrict__ o_hpi, float* __restrict__ o_cpi)
{
    __shared__ float red[256];
    const int n = blockIdx.x, t = threadIdx.x;
    float a = 0.f;
    for (int j = 0; j < 8; ++j)
        a = fmaxf(a, starts[(size_t)n * TSEQ + t * 8 + j]);
    red[t] = a; __syncthreads();
    for (int s = 128; s > 0; s >>= 1) {
        if (t < s) red[t] = fmaxf(red[t], red[t + s]);
        __syncthreads();
    }
    float m = (red[0] > 0.f) ? 0.f : 1.f;
    o_hpi[(size_t)n * 256 + t] = h_pi[(size_t)n * 256 + t] * m;
    o_cpi[(size_t)n * 256 + t] = c_pi[(size_t)n * 256 + t] * m;
}

// ---------------------------------------------------------------------------
// policy_finish (chunk): logits (fp64 dot) -> argmax, log-softmax pick.
// ---------------------------------------------------------------------------
__global__ __launch_bounds__(256)
void policy_finish(const float* __restrict__ h1p, const float* __restrict__ Wp2,
                   const float* __restrict__ bp2,
                   float* __restrict__ o_actions, float* __restrict__ o_logp,
                   int base)
{
    __shared__ float w2t[512 * 32];   // [k][c]
    const int t = threadIdx.x;
    for (int j = 0; j < 64; ++j) {
        int idx = t + 256 * j;
        int k = idx >> 5, c = idx & 31;
        w2t[idx] = Wp2[(size_t)c * 512 + k];
    }
    __syncthreads();

    const int c = t & 31;
    size_t lr = (size_t)blockIdx.x * 8 + (t >> 5);
    size_t grow = (lr >> 7) * TSEQ + base + (lr & 127);
    const float* hrow = h1p + lr * 512;
    double s = 0.0;
    for (int k = 0; k < 512; k += 4) {
        float4 h4 = *(const float4*)(hrow + k);
        s += (double)h4.x * (double)w2t[(k + 0) * 32 + c];
        s += (double)h4.y * (double)w2t[(k + 1) * 32 + c];
        s += (double)h4.z * (double)w2t[(k + 2) * 32 + c];
        s += (double)h4.w * (double)w2t[(k + 3) * 32 + c];
    }
    double logit = s + (double)bp2[c];

    double mv = logit; int mi = c;
#pragma unroll
    for (int off = 16; off >= 1; off >>= 1) {
        double ov = __shfl_xor(mv, off, 32);
        int    oi = __shfl_xor(mi, off, 32);
        if (ov > mv || (ov == mv && oi < mi)) { mv = ov; mi = oi; }
    }
    double se = exp(logit - mv);
#pragma unroll
    for (int off = 16; off >= 1; off >>= 1) se += __shfl_xor(se, off, 32);

    if (c == 0) {
        o_actions[grow] = (float)mi;
        o_logp[grow]    = (float)(-log(se));
    }
}

// ---------------------------------------------------------------------------
// value_finish (chunk): values = h1v . Wv2 + bv2. 64 rows x 4 lanes; 128 blocks.
// ---------------------------------------------------------------------------
__global__ __launch_bounds__(256)
void value_finish(const float* __restrict__ h1v, const float* __restrict__ Wv2,
                  const float* __restrict__ bv2, float* __restrict__ o_values,
                  int base)
{
    __shared__ float wv[512];
    const int t = threadIdx.x;
    wv[t] = Wv2[t]; wv[t + 256] = Wv2[t + 256];
    __syncthreads();
    const int q = t & 3;
    size_t lr = (size_t)blockIdx.x * 64 + (t >> 2);
    size_t grow = (lr >> 7) * TSEQ + base + (lr & 127);
    const float* hrow = h1v + lr * 512;
    float s = 0.f;
    for (int k = q * 128; k < q * 128 + 128; k += 4) {
        float4 h4 = *(const float4*)(hrow + k);
        float4 w4 = *(const float4*)&wv[k];
        s += h4.x * w4.x + h4.y * w4.y + h4.z * w4.z + h4.w * w4.w;
    }
    s += __shfl_xor(s, 1, 4);
    s += __shfl_xor(s, 2, 4);
    if (q == 0) o_values[grow] = s + bv2[0];
}

// ---------------------------------------------------------------------------
extern "C" void kernel_launch(void* const* d_in, const int* in_sizes, int n_in,
                              void* d_out, int out_size, void* d_ws, size_t ws_size,
                              hipStream_t stream)
{
    const float* features = (const float*)d_in[0];
    const float* starts   = (const float*)d_in[1];
    const float* h_pi     = (const float*)d_in[2];
    const float* c_pi     = (const float*)d_in[3];
    const float* h_vf     = (const float*)d_in[4];
    const float* c_vf     = (const float*)d_in[5];
    const float* W_feat   = (const float*)d_in[6];
    const float* b_feat   = (const float*)d_in[7];
    const float* W_emb    = (const float*)d_in[8];
    const float* b_emb    = (const float*)d_in[9];
    const float* W_ih     = (const float*)d_in[10];
    const float* W_hh     = (const float*)d_in[11];
    const float* b_ih     = (const float*)d_in[12];
    const float* b_hh     = (const float*)d_in[13];
    const float* Wp1      = (const float*)d_in[14];
    const float* bp1      = (const float*)d_in[15];
    const float* Wp2      = (const float*)d_in[16];
    const float* bp2      = (const float*)d_in[17];
    const float* Wv1      = (const float*)d_in[18];
    const float* bv1      = (const float*)d_in[19];
    const float* Wv2      = (const float*)d_in[20];
    const float* bv2      = (const float*)d_in[21];

    float* out = (float*)d_out;
    float* o_actions = out;
    float* o_values  = out + N_TOT;
    float* o_logp    = out + 2 * (size_t)N_TOT;
    float* o_hpi     = out + 3 * (size_t)N_TOT;
    float* o_cpi     = o_hpi + NSEQ * 256;
    float* o_hT      = o_cpi + NSEQ * 256;
    float* o_cT      = o_hT  + NSEQ * 256;

    // workspace (~90 MB)
    char* ws = (char*)d_ws;
    const size_t MB = 1024 * 1024;
    float* xg_c  = (float*)(ws);                 // 32 MB  (8192 x 1024)
    float* lat_c = (float*)(ws + 32 * MB);       // 32 MB  (8192 x 1024)
    float* hs_c  = (float*)(ws + 64 * MB);       //  8 MB  (8192 x 256)
    float* h1_c  = (float*)(ws + 72 * MB);       // 16 MB  (8192 x 512)
    float* Wg    = (float*)(ws + 88 * MB);       //  1 MB
    float* hstate = (float*)(ws + 89 * MB);                  // 64 KB
    float* cstate = (float*)(ws + 89 * MB + 65536);          // 64 KB
    float* hx     = (float*)(ws + 89 * MB + 131072);         // 128 KB (2x64x256)
    unsigned int* flags = (unsigned int*)(ws + 89 * MB + 262144); // 512 KB

    zero_u32<<<(NSEQ * TSEQ + 255) / 256, 256, 0, stream>>>(flags, NSEQ * TSEQ);

    transpose_whh<<<256, 256, 0, stream>>>(W_hh, Wg);

    mask_kernel<<<NSEQ, 256, 0, stream>>>(starts, h_pi, c_pi, o_hpi, o_cpi);

    for (int c = 0; c < NCH; ++c) {
        const int base = c * CS;

        gemm_xg<<<dim3(8, NSEQ), 256, 0, stream>>>(features, W_ih, b_ih, b_hh,
                                                   xg_c, base);
        lstm3<<<NSEQ * PARTS, 1024, 0, stream>>>(xg_c, starts, h_vf, c_vf,
                                                 hstate, cstate, Wg,
                                                 hs_c, o_hT, o_cT,
                                                 hx, flags, base);

        gemm_latent<<<dim3(16, 128), 256, 0, stream>>>(
            features, W_feat, W_emb, b_feat, b_emb, lat_c, base);

        gemm_h1p<<<dim3(8, 128), 256, 0, stream>>>(lat_c, Wp1, bp1, h1_c);
        policy_finish<<<1024, 256, 0, stream>>>(h1_c, Wp2, bp2,
                                                o_actions, o_logp, base);

        gemm_h1v<<<dim3(4, 64), 256, 0, stream>>>(lat_c, hs_c, Wv1, bv1, h1_c);
        value_finish<<<128, 256, 0, stream>>>(h1_c, Wv2, bv2, o_values, base);
    }
}

// Round 6
// 16597.839 us; speedup vs baseline: 2.8928x; 1.4059x over previous
//
#include <hip/hip_runtime.h>
#include <stdint.h>
#include <math.h>

#define N_TOT 131072   // NSEQ * T
#define TSEQ  2048
#define NSEQ  64
#define CS    128      // chunk steps
#define NCH   16       // chunks
#define PARTS 4        // WGs per sequence

typedef unsigned long long u64;

// ---------------------------------------------------------------------------
// One-time: transpose W_hh (1024x256, row = gate*256+u) into
// Wg[k][u][gate]  (k-major, unit, 4 gates contiguous).
// ---------------------------------------------------------------------------
__global__ __launch_bounds__(256)
void transpose_whh(const float* __restrict__ Whh, float* __restrict__ Wg)
{
    const int k = blockIdx.x;     // 0..255
    const int u = threadIdx.x;    // 0..255
#pragma unroll
    for (int g = 0; g < 4; ++g)
        Wg[(size_t)k * 1024 + u * 4 + g] = Whh[(size_t)(g * 256 + u) * 256 + k];
}

// ---------------------------------------------------------------------------
// gemm_xg (chunk): xg[lr][u*4+g] = feats @ W_ih^T + b_ih + b_hh  (permuted)
// grid (8, 64): bx = n-tile, by = seq. fp32, 128x128 tile, 8x8 reg block.
// ---------------------------------------------------------------------------
__global__ __launch_bounds__(256)
void gemm_xg(const float* __restrict__ A, const float* __restrict__ Wih,
             const float* __restrict__ bih, const float* __restrict__ bhh,
             float* __restrict__ xg, int base)
{
    __shared__ float As[16][136];
    __shared__ float Bs[16][136];
    const int t  = threadIdx.x;
    const int n0 = blockIdx.x * 128;
    const int seq = blockIdx.y;
    const size_t grow0 = (size_t)seq * TSEQ + base;
    const size_t lrow0 = (size_t)seq * CS;
    const int tx = t & 15, ty = t >> 4;

    float acc[8][8];
#pragma unroll
    for (int i = 0; i < 8; ++i)
#pragma unroll
        for (int j = 0; j < 8; ++j) acc[i][j] = 0.f;

    for (int kt = 0; kt < 256; kt += 16) {
#pragma unroll
        for (int jj = 0; jj < 2; ++jj) {
            int idx = t + 256 * jj;
            int m = idx >> 2, q = idx & 3;
            float4 a = *(const float4*)(A + (grow0 + m) * 256 + kt + q * 4);
            As[q * 4 + 0][m] = a.x; As[q * 4 + 1][m] = a.y;
            As[q * 4 + 2][m] = a.z; As[q * 4 + 3][m] = a.w;
            float4 b = *(const float4*)(Wih + (size_t)(n0 + m) * 256 + kt + q * 4);
            Bs[q * 4 + 0][m] = b.x; Bs[q * 4 + 1][m] = b.y;
            Bs[q * 4 + 2][m] = b.z; Bs[q * 4 + 3][m] = b.w;
        }
        __syncthreads();
#pragma unroll
        for (int k = 0; k < 16; ++k) {
            float4 a0 = *(const float4*)&As[k][ty * 8];
            float4 a1 = *(const float4*)&As[k][ty * 8 + 4];
            float4 b0 = *(const float4*)&Bs[k][tx * 8];
            float4 b1 = *(const float4*)&Bs[k][tx * 8 + 4];
            float av[8] = {a0.x, a0.y, a0.z, a0.w, a1.x, a1.y, a1.z, a1.w};
            float bv[8] = {b0.x, b0.y, b0.z, b0.w, b1.x, b1.y, b1.z, b1.w};
#pragma unroll
            for (int i = 0; i < 8; ++i)
#pragma unroll
                for (int j = 0; j < 8; ++j) acc[i][j] += av[i] * bv[j];
        }
        __syncthreads();
    }
#pragma unroll
    for (int i = 0; i < 8; ++i) {
        size_t lr = lrow0 + ty * 8 + i;
#pragma unroll
        for (int j = 0; j < 8; ++j) {
            int n = n0 + tx * 8 + j;      // gate-major index 0..1023
            int gate = n >> 8, u = n & 255;
            xg[lr * 1024 + u * 4 + gate] = acc[i][j] + bih[n] + bhh[n];
        }
    }
}

// ---------------------------------------------------------------------------
// lstm4: register-resident weights, tagged-word h exchange.
// 256 WGs = 64 seqs x 4 parts (64 units each). Thread (u=t&63, q=t>>6) holds
// W[k in q*16..+16) x 4 gates] = 16 float4 in VGPRs.
// h exchange: one u64 per unit = (step_tag<<32)|float_bits, relaxed agent
// atomics, parity double-buffer. Single one-way visibility per step.
// ---------------------------------------------------------------------------
__global__ __launch_bounds__(1024)
void lstm4(const float* __restrict__ xg, const float* __restrict__ starts,
           const float* __restrict__ h0g, const float* __restrict__ c0g,
           float* __restrict__ hstate, float* __restrict__ cstate,
           const float* __restrict__ Wg,
           float* __restrict__ hs, float* __restrict__ hT,
           float* __restrict__ cT,
           u64* __restrict__ hx, int base)
{
    __shared__ float hmask[256];
    __shared__ float part[16][64][4];   // 16 KB

    const int t   = threadIdx.x;
    const int seq = blockIdx.x >> 2;
    const int p   = blockIdx.x & 3;
    const int u   = t & 63;
    const int q   = t >> 6;            // 0..15 (wave-uniform)

    // weights into registers: 16 float4 (64 VGPRs)
    float4 Wr[16];
#pragma unroll
    for (int kk = 0; kk < 16; ++kk)
        Wr[kk] = *(const float4*)(Wg + (size_t)(q * 16 + kk) * 1024 + (p * 64 + u) * 4);

    float c_reg = 0.f;
    if (t < 64) {
        const float* csrc = (base == 0) ? c0g : cstate;
        c_reg = csrc[(size_t)seq * 256 + p * 64 + t];
    }

    for (int lt = 0; lt < CS; ++lt) {
        const int S = base + lt;
        const float m = 1.f - starts[(size_t)seq * TSEQ + S];

        // prefetch xg for owners (independent of exchange)
        float4 x4 = make_float4(0.f, 0.f, 0.f, 0.f);
        if (t < 64)
            x4 = *(const float4*)(xg + ((size_t)seq * CS + lt) * 1024 + (p * 64 + t) * 4);

        if (lt == 0) {
            if (t < 256) {
                const float* hsrc = (base == 0) ? h0g : hstate;
                hmask[t] = hsrc[(size_t)seq * 256 + t] * m;
            }
        } else {
            if (t < 256) {
                const size_t idx = (size_t)(S & 1) * (NSEQ * 256) + (size_t)seq * 256 + t;
                u64 w; unsigned spins = 0;
                for (;;) {
                    w = __hip_atomic_load(&hx[idx], __ATOMIC_RELAXED,
                                          __HIP_MEMORY_SCOPE_AGENT);
                    if ((unsigned)(w >> 32) == (unsigned)S) break;
                    __builtin_amdgcn_s_sleep(1);
                    if (++spins > (1u << 20)) break;   // safety valve
                }
                hmask[t] = __uint_as_float((unsigned)w) * m;
            }
        }
        __syncthreads();   // A: hmask ready

        // partial dot over k in [q*16, q*16+16) for unit u, 4 gates
        const float* hp = &hmask[q * 16];
        float4 h0 = *(const float4*)(hp + 0);
        float4 h1 = *(const float4*)(hp + 4);
        float4 h2 = *(const float4*)(hp + 8);
        float4 h3 = *(const float4*)(hp + 12);
        float hv[16] = {h0.x,h0.y,h0.z,h0.w, h1.x,h1.y,h1.z,h1.w,
                        h2.x,h2.y,h2.z,h2.w, h3.x,h3.y,h3.z,h3.w};
        float a0 = 0.f, a1 = 0.f, a2 = 0.f, a3 = 0.f;
#pragma unroll
        for (int kk = 0; kk < 16; ++kk) {
            a0 += hv[kk] * Wr[kk].x;
            a1 += hv[kk] * Wr[kk].y;
            a2 += hv[kk] * Wr[kk].z;
            a3 += hv[kk] * Wr[kk].w;
        }
        *(float4*)&part[q][u][0] = make_float4(a0, a1, a2, a3);
        __syncthreads();   // B: partials ready

        if (t < 64) {
            float gi = 0.f, gf = 0.f, gg = 0.f, go = 0.f;
#pragma unroll
            for (int qq = 0; qq < 16; ++qq) {
                float4 pp = *(const float4*)&part[qq][t][0];
                gi += pp.x; gf += pp.y; gg += pp.z; go += pp.w;
            }
            gi += x4.x; gf += x4.y; gg += x4.z; go += x4.w;
            float c = c_reg * m;
            float si = 1.f / (1.f + expf(-gi));
            float sf = 1.f / (1.f + expf(-gf));
            float so = 1.f / (1.f + expf(-go));
            c = sf * c + si * tanhf(gg);
            float h = so * tanhf(c);
            c_reg = c;

            const int gu = p * 64 + t;
            const size_t widx = (size_t)((S + 1) & 1) * (NSEQ * 256)
                              + (size_t)seq * 256 + gu;
            __hip_atomic_store(&hx[widx],
                               ((u64)(unsigned)(S + 1) << 32) |
                               (u64)__float_as_uint(h),
                               __ATOMIC_RELAXED, __HIP_MEMORY_SCOPE_AGENT);
            hs[((size_t)seq * CS + lt) * 256 + gu] = h;
            if (lt == CS - 1) {
                cstate[(size_t)seq * 256 + gu] = c;
                hstate[(size_t)seq * 256 + gu] = h;
            }
            if (S == TSEQ - 1) {
                cT[(size_t)seq * 256 + gu] = c;
                hT[(size_t)seq * 256 + gu] = h;
            }
        }
        // no trailing barrier needed: next iteration's first barrier (A)
        // orders part[]/hmask reuse; hx poll is global-tag-gated.
    }
}

// ---------------------------------------------------------------------------
// gemm_latent (chunk): lat[lr][n] (n<768: feats@W_feat^T + b_feat;
// n>=768: feats@W_emb^T + b_emb). fp64 masters, 64x64 tile, 4x4/thread.
// ---------------------------------------------------------------------------
__global__ __launch_bounds__(256)
void gemm_latent(const float* __restrict__ A, const float* __restrict__ Wfeat,
                 const float* __restrict__ Wemb, const float* __restrict__ bfeat,
                 const float* __restrict__ bemb, float* __restrict__ lat, int base)
{
    __shared__ float As[16][72];
    __shared__ float Bs[16][72];
    const int t  = threadIdx.x;
    const int n0 = blockIdx.x * 64;
    const size_t lr0 = (size_t)blockIdx.y * 64;
    const size_t grow0 = (lr0 >> 7) * TSEQ + base + (lr0 & 127);
    const int tx = t & 15, ty = t >> 4;

    double acc[4][4];
#pragma unroll
    for (int i = 0; i < 4; ++i)
#pragma unroll
        for (int j = 0; j < 4; ++j) acc[i][j] = 0.0;

    for (int kt = 0; kt < 256; kt += 16) {
        {
            int m = t >> 2, q = t & 3;
            float4 a = *(const float4*)(A + (grow0 + m) * 256 + kt + q * 4);
            As[q * 4 + 0][m] = a.x; As[q * 4 + 1][m] = a.y;
            As[q * 4 + 2][m] = a.z; As[q * 4 + 3][m] = a.w;
            int n = n0 + m;
            const float* Brow = (n < 768) ? (Wfeat + (size_t)n * 256)
                                          : (Wemb + (size_t)(n - 768) * 256);
            float4 b = *(const float4*)(Brow + kt + q * 4);
            Bs[q * 4 + 0][m] = b.x; Bs[q * 4 + 1][m] = b.y;
            Bs[q * 4 + 2][m] = b.z; Bs[q * 4 + 3][m] = b.w;
        }
        __syncthreads();
        float p[4][4];
#pragma unroll
        for (int i = 0; i < 4; ++i)
#pragma unroll
            for (int j = 0; j < 4; ++j) p[i][j] = 0.f;
#pragma unroll
        for (int k = 0; k < 16; ++k) {
            float4 a0 = *(const float4*)&As[k][ty * 4];
            float4 b0 = *(const float4*)&Bs[k][tx * 4];
            float av[4] = {a0.x, a0.y, a0.z, a0.w};
            float bv[4] = {b0.x, b0.y, b0.z, b0.w};
#pragma unroll
            for (int i = 0; i < 4; ++i)
#pragma unroll
                for (int j = 0; j < 4; ++j) p[i][j] += av[i] * bv[j];
        }
#pragma unroll
        for (int i = 0; i < 4; ++i)
#pragma unroll
            for (int j = 0; j < 4; ++j) acc[i][j] += (double)p[i][j];
        __syncthreads();
    }
#pragma unroll
    for (int i = 0; i < 4; ++i) {
        size_t lr = lr0 + ty * 4 + i;
#pragma unroll
        for (int j = 0; j < 4; ++j) {
            int n = n0 + tx * 4 + j;
            float v = (float)acc[i][j];
            v += (n < 768) ? bfeat[n] : bemb[n - 768];
            lat[lr * 1024 + n] = v;
        }
    }
}

// ---------------------------------------------------------------------------
// gemm_h1p (chunk): h1[lr][n] = relu(lat[lr] @ Wp1[n]^T + bp1[n]), K=1024.
// fp64 masters, 64x64 tile, 4x4/thread. grid (8, 128).
// ---------------------------------------------------------------------------
__global__ __launch_bounds__(256)
void gemm_h1p(const float* __restrict__ lat, const float* __restrict__ Wp1,
              const float* __restrict__ bp1, float* __restrict__ h1)
{
    __shared__ float As[16][72];
    __shared__ float Bs[16][72];
    const int t  = threadIdx.x;
    const int n0 = blockIdx.x * 64;
    const size_t lr0 = (size_t)blockIdx.y * 64;
    const int tx = t & 15, ty = t >> 4;

    double acc[4][4];
#pragma unroll
    for (int i = 0; i < 4; ++i)
#pragma unroll
        for (int j = 0; j < 4; ++j) acc[i][j] = 0.0;

    for (int kt = 0; kt < 1024; kt += 16) {
        {
            int m = t >> 2, q = t & 3;
            float4 a = *(const float4*)(lat + (lr0 + m) * 1024 + kt + q * 4);
            As[q * 4 + 0][m] = a.x; As[q * 4 + 1][m] = a.y;
            As[q * 4 + 2][m] = a.z; As[q * 4 + 3][m] = a.w;
            float4 b = *(const float4*)(Wp1 + (size_t)(n0 + m) * 1024 + kt + q * 4);
            Bs[q * 4 + 0][m] = b.x; Bs[q * 4 + 1][m] = b.y;
            Bs[q * 4 + 2][m] = b.z; Bs[q * 4 + 3][m] = b.w;
        }
        __syncthreads();
        float p[4][4];
#pragma unroll
        for (int i = 0; i < 4; ++i)
#pragma unroll
            for (int j = 0; j < 4; ++j) p[i][j] = 0.f;
#pragma unroll
        for (int k = 0; k < 16; ++k) {
            float4 a0 = *(const float4*)&As[k][ty * 4];
            float4 b0 = *(const float4*)&Bs[k][tx * 4];
            float av[4] = {a0.x, a0.y, a0.z, a0.w};
            float bv[4] = {b0.x, b0.y, b0.z, b0.w};
#pragma unroll
            for (int i = 0; i < 4; ++i)
#pragma unroll
                for (int j = 0; j < 4; ++j) p[i][j] += av[i] * bv[j];
        }
#pragma unroll
        for (int i = 0; i < 4; ++i)
#pragma unroll
            for (int j = 0; j < 4; ++j) acc[i][j] += (double)p[i][j];
        __syncthreads();
    }
#pragma unroll
    for (int i = 0; i < 4; ++i) {
        size_t lr = lr0 + ty * 4 + i;
#pragma unroll
        for (int j = 0; j < 4; ++j) {
            int n = n0 + tx * 4 + j;
            float v = (float)acc[i][j] + bp1[n];
            h1[lr * 512 + n] = v > 0.f ? v : 0.f;
        }
    }
}

// ---------------------------------------------------------------------------
// gemm_h1v (chunk): h1[lr][n] = relu(lat[lr][0:768]@Wv1[n][0:768]^T
//                                  + hs[lr]@Wv1[n][768:]^T + bv1[n])  fp32
// grid (4, 64): 128x128 tile, 8x8/thread.
// ---------------------------------------------------------------------------
__global__ __launch_bounds__(256)
void gemm_h1v(const float* __restrict__ lat, const float* __restrict__ hs,
              const float* __restrict__ Wv1, const float* __restrict__ bv1,
              float* __restrict__ h1)
{
    __shared__ float As[16][136];
    __shared__ float Bs[16][136];
    const int t  = threadIdx.x;
    const int n0 = blockIdx.x * 128;
    const size_t lrow0 = (size_t)blockIdx.y * 128;
    const int tx = t & 15, ty = t >> 4;

    float acc[8][8];
#pragma unroll
    for (int i = 0; i < 8; ++i)
#pragma unroll
        for (int j = 0; j < 8; ++j) acc[i][j] = 0.f;

    for (int pass = 0; pass < 2; ++pass) {
        const float* A  = (pass == 0) ? lat : hs;
        const int lda   = (pass == 0) ? 1024 : 256;
        const int kmax  = (pass == 0) ? 768 : 256;
        const int boff  = (pass == 0) ? 0 : 768;
        for (int kt = 0; kt < kmax; kt += 16) {
#pragma unroll
            for (int jj = 0; jj < 2; ++jj) {
                int idx = t + 256 * jj;
                int m = idx >> 2, q = idx & 3;
                float4 a = *(const float4*)(A + (lrow0 + m) * lda + kt + q * 4);
                As[q * 4 + 0][m] = a.x; As[q * 4 + 1][m] = a.y;
                As[q * 4 + 2][m] = a.z; As[q * 4 + 3][m] = a.w;
                float4 b = *(const float4*)(Wv1 + (size_t)(n0 + m) * 1024 + boff + kt + q * 4);
                Bs[q * 4 + 0][m] = b.x; Bs[q * 4 + 1][m] = b.y;
                Bs[q * 4 + 2][m] = b.z; Bs[q * 4 + 3][m] = b.w;
            }
            __syncthreads();
#pragma unroll
            for (int k = 0; k < 16; ++k) {
                float4 a0 = *(const float4*)&As[k][ty * 8];
                float4 a1 = *(const float4*)&As[k][ty * 8 + 4];
                float4 b0 = *(const float4*)&Bs[k][tx * 8];
                float4 b1 = *(const float4*)&Bs[k][tx * 8 + 4];
                float av[8] = {a0.x, a0.y, a0.z, a0.w, a1.x, a1.y, a1.z, a1.w};
                float bv[8] = {b0.x, b0.y, b0.z, b0.w, b1.x, b1.y, b1.z, b1.w};
#pragma unroll
                for (int i = 0; i < 8; ++i)
#pragma unroll
                    for (int j = 0; j < 8; ++j) acc[i][j] += av[i] * bv[j];
            }
            __syncthreads();
        }
    }
#pragma unroll
    for (int i = 0; i < 8; ++i) {
        size_t lr = lrow0 + ty * 8 + i;
#pragma unroll
        for (int j = 0; j < 8; ++j) {
            int n = n0 + tx * 8 + j;
            float v = acc[i][j] + bv1[n];
            h1[lr * 512 + n] = v > 0.f ? v : 0.f;
        }
    }
}

// ---------------------------------------------------------------------------
__global__ __launch_bounds__(256)
void mask_kernel(const float* __restrict__ starts, const float* __restrict__ h_pi,
                 const float* __restrict__ c_pi,
                 float* __restrict__ o_hpi, float* __restrict__ o_cpi)
{
    __shared__ float red[256];
    const int n = blockIdx.x, t = threadIdx.x;
    float a = 0.f;
    for (int j = 0; j < 8; ++j)
        a = fmaxf(a, starts[(size_t)n * TSEQ + t * 8 + j]);
    red[t] = a; __syncthreads();
    for (int s = 128; s > 0; s >>= 1) {
        if (t < s) red[t] = fmaxf(red[t], red[t + s]);
        __syncthreads();
    }
    float m = (red[0] > 0.f) ? 0.f : 1.f;
    o_hpi[(size_t)n * 256 + t] = h_pi[(size_t)n * 256 + t] * m;
    o_cpi[(size_t)n * 256 + t] = c_pi[(size_t)n * 256 + t] * m;
}

// ---------------------------------------------------------------------------
// policy_finish (chunk): logits (fp64 dot) -> argmax, log-softmax pick.
// ---------------------------------------------------------------------------
__global__ __launch_bounds__(256)
void policy_finish(const float* __restrict__ h1p, const float* __restrict__ Wp2,
                   const float* __restrict__ bp2,
                   float* __restrict__ o_actions, float* __restrict__ o_logp,
                   int base)
{
    __shared__ float w2t[512 * 32];   // [k][c]
    const int t = threadIdx.x;
    for (int j = 0; j < 64; ++j) {
        int idx = t + 256 * j;
        int k = idx >> 5, c = idx & 31;
        w2t[idx] = Wp2[(size_t)c * 512 + k];
    }
    __syncthreads();

    const int c = t & 31;
    size_t lr = (size_t)blockIdx.x * 8 + (t >> 5);
    size_t grow = (lr >> 7) * TSEQ + base + (lr & 127);
    const float* hrow = h1p + lr * 512;
    double s = 0.0;
    for (int k = 0; k < 512; k += 4) {
        float4 h4 = *(const float4*)(hrow + k);
        s += (double)h4.x * (double)w2t[(k + 0) * 32 + c];
        s += (double)h4.y * (double)w2t[(k + 1) * 32 + c];
        s += (double)h4.z * (double)w2t[(k + 2) * 32 + c];
        s += (double)h4.w * (double)w2t[(k + 3) * 32 + c];
    }
    double logit = s + (double)bp2[c];

    double mv = logit; int mi = c;
#pragma unroll
    for (int off = 16; off >= 1; off >>= 1) {
        double ov = __shfl_xor(mv, off, 32);
        int    oi = __shfl_xor(mi, off, 32);
        if (ov > mv || (ov == mv && oi < mi)) { mv = ov; mi = oi; }
    }
    double se = exp(logit - mv);
#pragma unroll
    for (int off = 16; off >= 1; off >>= 1) se += __shfl_xor(se, off, 32);

    if (c == 0) {
        o_actions[grow] = (float)mi;
        o_logp[grow]    = (float)(-log(se));
    }
}

// ---------------------------------------------------------------------------
// value_finish (chunk): values = h1v . Wv2 + bv2. 64 rows x 4 lanes; 128 blocks.
// ---------------------------------------------------------------------------
__global__ __launch_bounds__(256)
void value_finish(const float* __restrict__ h1v, const float* __restrict__ Wv2,
                  const float* __restrict__ bv2, float* __restrict__ o_values,
                  int base)
{
    __shared__ float wv[512];
    const int t = threadIdx.x;
    wv[t] = Wv2[t]; wv[t + 256] = Wv2[t + 256];
    __syncthreads();
    const int q = t & 3;
    size_t lr = (size_t)blockIdx.x * 64 + (t >> 2);
    size_t grow = (lr >> 7) * TSEQ + base + (lr & 127);
    const float* hrow = h1v + lr * 512;
    float s = 0.f;
    for (int k = q * 128; k < q * 128 + 128; k += 4) {
        float4 h4 = *(const float4*)(hrow + k);
        float4 w4 = *(const float4*)&wv[k];
        s += h4.x * w4.x + h4.y * w4.y + h4.z * w4.z + h4.w * w4.w;
    }
    s += __shfl_xor(s, 1, 4);
    s += __shfl_xor(s, 2, 4);
    if (q == 0) o_values[grow] = s + bv2[0];
}

// ---------------------------------------------------------------------------
extern "C" void kernel_launch(void* const* d_in, const int* in_sizes, int n_in,
                              void* d_out, int out_size, void* d_ws, size_t ws_size,
                              hipStream_t stream)
{
    const float* features = (const float*)d_in[0];
    const float* starts   = (const float*)d_in[1];
    const float* h_pi     = (const float*)d_in[2];
    const float* c_pi     = (const float*)d_in[3];
    const float* h_vf     = (const float*)d_in[4];
    const float* c_vf     = (const float*)d_in[5];
    const float* W_feat   = (const float*)d_in[6];
    const float* b_feat   = (const float*)d_in[7];
    const float* W_emb    = (const float*)d_in[8];
    const float* b_emb    = (const float*)d_in[9];
    const float* W_ih     = (const float*)d_in[10];
    const float* W_hh     = (const float*)d_in[11];
    const float* b_ih     = (const float*)d_in[12];
    const float* b_hh     = (const float*)d_in[13];
    const float* Wp1      = (const float*)d_in[14];
    const float* bp1      = (const float*)d_in[15];
    const float* Wp2      = (const float*)d_in[16];
    const float* bp2      = (const float*)d_in[17];
    const float* Wv1      = (const float*)d_in[18];
    const float* bv1      = (const float*)d_in[19];
    const float* Wv2      = (const float*)d_in[20];
    const float* bv2      = (const float*)d_in[21];

    float* out = (float*)d_out;
    float* o_actions = out;
    float* o_values  = out + N_TOT;
    float* o_logp    = out + 2 * (size_t)N_TOT;
    float* o_hpi     = out + 3 * (size_t)N_TOT;
    float* o_cpi     = o_hpi + NSEQ * 256;
    float* o_hT      = o_cpi + NSEQ * 256;
    float* o_cT      = o_hT  + NSEQ * 256;

    // workspace (~89.5 MB)
    char* ws = (char*)d_ws;
    const size_t MB = 1024 * 1024;
    float* xg_c  = (float*)(ws);                 // 32 MB  (8192 x 1024)
    float* lat_c = (float*)(ws + 32 * MB);       // 32 MB  (8192 x 1024)
    float* hs_c  = (float*)(ws + 64 * MB);       //  8 MB  (8192 x 256)
    float* h1_c  = (float*)(ws + 72 * MB);       // 16 MB  (8192 x 512)
    float* Wg    = (float*)(ws + 88 * MB);       //  1 MB
    float* hstate = (float*)(ws + 89 * MB);                  // 64 KB
    float* cstate = (float*)(ws + 89 * MB + 65536);          // 64 KB
    u64*   hx     = (u64*)  (ws + 89 * MB + 131072);         // 256 KB (2x64x256 u64)

    transpose_whh<<<256, 256, 0, stream>>>(W_hh, Wg);

    mask_kernel<<<NSEQ, 256, 0, stream>>>(starts, h_pi, c_pi, o_hpi, o_cpi);

    for (int c = 0; c < NCH; ++c) {
        const int base = c * CS;

        gemm_xg<<<dim3(8, NSEQ), 256, 0, stream>>>(features, W_ih, b_ih, b_hh,
                                                   xg_c, base);
        lstm4<<<NSEQ * PARTS, 1024, 0, stream>>>(xg_c, starts, h_vf, c_vf,
                                                 hstate, cstate, Wg,
                                                 hs_c, o_hT, o_cT, hx, base);

        gemm_latent<<<dim3(16, 128), 256, 0, stream>>>(
            features, W_feat, W_emb, b_feat, b_emb, lat_c, base);

        gemm_h1p<<<dim3(8, 128), 256, 0, stream>>>(lat_c, Wp1, bp1, h1_c);
        policy_finish<<<1024, 256, 0, stream>>>(h1_c, Wp2, bp2,
                                                o_actions, o_logp, base);

        gemm_h1v<<<dim3(4, 64), 256, 0, stream>>>(lat_c, hs_c, Wv1, bv1, h1_c);
        value_finish<<<128, 256, 0, stream>>>(h1_c, Wv2, bv2, o_values, base);
    }
}